// Round 3
// baseline (7530.702 us; speedup 1.0000x reference)
//
#include <hip/hip_runtime.h>
#include <math.h>

static constexpr int V  = 1024;
static constexpr int NH = 256;
static constexpr int B  = 128;
static constexpr int T  = 512;
static constexpr size_t BV  = (size_t)B * V;
static constexpr size_t YSZ = (size_t)T * B * V;   // 67,108,864

typedef _Float16 h8 __attribute__((ext_vector_type(8)));
typedef _Float16 h4 __attribute__((ext_vector_type(4)));
typedef float f32x4 __attribute__((ext_vector_type(4)));

#define MFMA16(a, b, c) __builtin_amdgcn_mfma_f32_16x16x32_f16((a), (b), (c), 0, 0, 0)

// Split-f16: x = hi + lo*2^-11, lo pre-scaled by 2048. Dot = hi*hi + (hi*lo + lo*hi)*2^-11.
//
// d_out layout (f32): y[T*B][V], tails: H1[B][NH], C1, H2, C2.
// Recurrence stash: h2(t)->y[t][0:256], h1(t)->y[t][256:512] (overwritten by k_ygemm2).
// c1/c2 live in REGISTERS of their owning block; final values written to tails at t=T-1.
//
// d_ws: pk2 half[2][64][16][64][8], pk1 half[2][64][8][64][8], pkY half[2][64][8][64][8],
//       bp2 f32[1024], bp1 f32[1024], flagH1 int[512*8], flagH2 int[512*8].

__global__ __launch_bounds__(256) void k_prep(
    const float* __restrict__ W1f, const float* __restrict__ W1i,
    const float* __restrict__ W1o, const float* __restrict__ W1c,
    const float* __restrict__ W2f, const float* __restrict__ W2i,
    const float* __restrict__ W2o, const float* __restrict__ W2c,
    const float* __restrict__ Wout,
    const float* __restrict__ b1f, const float* __restrict__ b1i,
    const float* __restrict__ b1o, const float* __restrict__ b1c,
    const float* __restrict__ b2f, const float* __restrict__ b2i,
    const float* __restrict__ b2o, const float* __restrict__ b2c,
    _Float16* __restrict__ pk2, _Float16* __restrict__ pk1,
    _Float16* __restrict__ pkY, float* __restrict__ bp2, float* __restrict__ bp1)
{
    int idx = blockIdx.x * 256 + threadIdx.x;
    if (idx < 2097152) {
        int KB, e, rowoff = 0;
        bool vocabN = false;
        _Float16* dst;
        if (idx < 1048576)      { e = idx;            KB = 16; dst = pk2; }
        else if (idx < 1572864) { e = idx - 1048576;  KB = 8;  dst = pk1; rowoff = V; }
        else                    { e = idx - 1572864;  KB = 8;  dst = pkY; vocabN = true; }
        int S = 64 * KB * 512;
        int split = e / S, r = e % S;
        int grp = r / (KB * 512);
        int r2  = r % (KB * 512);
        int kb = r2 >> 9, lane = (r2 >> 3) & 63, i = r2 & 7;
        int n = grp * 16 + (lane & 15);
        int k = kb * 32 + (lane >> 4) * 8 + i;
        float val;
        if (vocabN) {
            val = Wout[(size_t)k * 1024 + n];
        } else {
            int j = n >> 2, g = n & 3;
            const float* W = (KB == 16)
                ? (g == 0 ? W2f : g == 1 ? W2i : g == 2 ? W2o : W2c)
                : (g == 0 ? W1f : g == 1 ? W1i : g == 2 ? W1o : W1c);
            val = W[(size_t)(rowoff + k) * NH + j];
        }
        _Float16 hi = (_Float16)val;
        dst[e] = split ? (_Float16)((val - (float)hi) * 2048.0f) : hi;
    } else {
        int bi = idx - 2097152;
        if (bi < 1024) {
            int j = bi >> 2, g = bi & 3;
            bp2[bi] = (g == 0 ? b2f : g == 1 ? b2i : g == 2 ? b2o : b2c)[j];
        } else if (bi < 2048) {
            int b2_ = bi - 1024;
            int j = b2_ >> 2, g = b2_ & 3;
            bp1[b2_] = (g == 0 ? b1f : g == 1 ? b1i : g == 2 ? b1o : b1c)[j];
        }
    }
}

__global__ __launch_bounds__(256) void k_zero(int* __restrict__ flags) {
    flags[blockIdx.x * 256 + threadIdx.x] = 0;
}

__device__ __forceinline__ void waitflag(int* f, int target) {
    while (__hip_atomic_load(f, __ATOMIC_ACQUIRE, __HIP_MEMORY_SCOPE_AGENT) < target) {}
}

// Persistent recurrence. 256 blocks: bid<128 -> cell2 role, else cell1 role.
// Block (mp,np) owns rows r0..r0+15, gate-cols np*64..+64 (16 hidden cols), all t.
__global__ __launch_bounds__(256, 1) void k_persist(
    const int* __restrict__ X,
    const float* __restrict__ H1in, const float* __restrict__ C1in,
    const float* __restrict__ H2in, const float* __restrict__ C2in,
    float* __restrict__ y,
    float* __restrict__ H1t, float* __restrict__ C1t,
    float* __restrict__ H2t, float* __restrict__ C2t,
    const _Float16* __restrict__ pk2, const _Float16* __restrict__ pk1,
    const float* __restrict__ bp2, const float* __restrict__ bp1,
    const float* __restrict__ W1f, const float* __restrict__ W1i,
    const float* __restrict__ W1o, const float* __restrict__ W1c,
    int* __restrict__ flagH1, int* __restrict__ flagH2)
{
    const int bid = blockIdx.x, tid = threadIdx.x;
    const bool isC2 = bid < 128;
    const int mp = (bid & 127) >> 4;    // 0..7
    const int np = bid & 15;            // 0..15
    const int r0 = mp * 16;

    __shared__ _Float16 Ah[16][520];
    __shared__ _Float16 Al[16][520];
    __shared__ float    pre[16][64];

    const int wave = tid >> 6, lane = tid & 63;
    const int col = lane & 15, kg = lane >> 4;
    const int KB = isC2 ? 16 : 8;
    const _Float16* pB = (isC2 ? pk2 : pk1) + ((size_t)((np * 4 + wave) * KB * 64) + lane) * 8;
    const size_t so = (size_t)64 * KB * 512;
    const _Float16* arow_h = &Ah[col][kg * 8];
    const _Float16* arow_l = &Al[col][kg * 8];

    const int cr = tid >> 4, cjl = tid & 15;
    const int cb = r0 + cr, cjg = np * 16 + cjl;
    float creg = isC2 ? C2in[cb * NH + cjg] : C1in[cb * NH + cjg];
    const f32x4 bb = *(const f32x4*)&((isC2 ? bp2 : bp1)[np * 64 + cjl * 4]);

    for (int t = 0; t < T; ++t) {
        // ---- wait for producers ----
        if (tid == 0) {
            if (isC2) {
                waitflag(&flagH1[t * 8 + mp], 16);
                if (t) waitflag(&flagH2[(t - 1) * 8 + mp], 16);
            } else {
                if (t) waitflag(&flagH1[(t - 1) * 8 + mp], 16);
            }
        }
        __syncthreads();

        // ---- stage A (split f32 -> hi/lo f16) ----
        if (isC2) {
            const float* h1p = y + (size_t)t * BV + 256;
            const float* h2p = t ? (y + (size_t)(t - 1) * BV) : H2in;
            const int h2s = t ? V : NH;
            for (int idx = tid; idx < 16 * 128; idx += 256) {
                int r = idx >> 7, k4 = idx & 127;
                const float* s = (k4 < 64)
                    ? h1p + (size_t)(r0 + r) * V + k4 * 4
                    : h2p + (size_t)(r0 + r) * h2s + (k4 - 64) * 4;
                f32x4 v = *(const f32x4*)s;
                h4 hi, lo;
                #pragma unroll
                for (int e = 0; e < 4; ++e) {
                    _Float16 h = (_Float16)v[e];
                    hi[e] = h; lo[e] = (_Float16)((v[e] - (float)h) * 2048.0f);
                }
                *(h4*)&Ah[r][k4 * 4] = hi;
                *(h4*)&Al[r][k4 * 4] = lo;
            }
        } else {
            const float* h1p = t ? (y + (size_t)(t - 1) * BV + 256) : H1in;
            const int h1s = t ? V : NH;
            for (int idx = tid; idx < 16 * 64; idx += 256) {
                int r = idx >> 6, k4 = idx & 63;
                f32x4 v = *(const f32x4*)(h1p + (size_t)(r0 + r) * h1s + k4 * 4);
                h4 hi, lo;
                #pragma unroll
                for (int e = 0; e < 4; ++e) {
                    _Float16 h = (_Float16)v[e];
                    hi[e] = h; lo[e] = (_Float16)((v[e] - (float)h) * 2048.0f);
                }
                *(h4*)&Ah[r][k4 * 4] = hi;
                *(h4*)&Al[r][k4 * 4] = lo;
            }
        }
        __syncthreads();

        // ---- MFMA: 16x16 out tile per wave ----
        f32x4 a0 = {0.f, 0.f, 0.f, 0.f}, a1 = a0, a2 = a0;
        for (int kb = 0; kb < KB; ++kb) {
            h8 ah = *(const h8*)(arow_h + kb * 32);
            h8 al = *(const h8*)(arow_l + kb * 32);
            h8 bh = *(const h8*)(pB + (size_t)kb * 512);
            h8 bl = *(const h8*)(pB + so + (size_t)kb * 512);
            a0 = MFMA16(ah, bh, a0);
            a1 = MFMA16(ah, bl, a1);
            a2 = MFMA16(al, bh, a2);
        }
        const int n_local = wave * 16 + col;
        #pragma unroll
        for (int q = 0; q < 4; ++q)
            pre[kg * 4 + q][n_local] = a0[q] + (a1[q] + a2[q]) * (1.0f / 2048.0f);
        __syncthreads();

        // ---- combine gates, update c (register), store h ----
        {
            f32x4 g = *(const f32x4*)&pre[cr][cjl * 4];
            float pf = g[0] + bb[0], pi = g[1] + bb[1], po = g[2] + bb[2], pc = g[3] + bb[3];
            if (!isC2) {
                int tok = X[cb * T + t];
                pf += W1f[(size_t)tok * NH + cjg];
                pi += W1i[(size_t)tok * NH + cjg];
                po += W1o[(size_t)tok * NH + cjg];
                pc += W1c[(size_t)tok * NH + cjg];
            }
            float fg = 1.f / (1.f + expf(-pf));
            float ig = 1.f / (1.f + expf(-pi));
            float og = 1.f / (1.f + expf(-po));
            float ct = tanhf(pc);
            creg = fmaf(fg, creg, ig * ct);
            float h = og * tanhf(creg);
            size_t dst = (size_t)t * BV + (size_t)cb * V + (isC2 ? 0 : 256) + cjg;
            __hip_atomic_store(&y[dst], h, __ATOMIC_RELAXED, __HIP_MEMORY_SCOPE_AGENT);
            if (t == T - 1) {
                if (isC2) { H2t[cb * NH + cjg] = h; C2t[cb * NH + cjg] = creg; }
                else      { H1t[cb * NH + cjg] = h; C1t[cb * NH + cjg] = creg; }
            }
        }
        __syncthreads();   // drains vmcnt(0): all h stores at agent scope before signal

        if (tid == 0) {
            int* f = (isC2 ? flagH2 : flagH1) + t * 8 + mp;
            __hip_atomic_fetch_add(f, 1, __ATOMIC_RELEASE, __HIP_MEMORY_SCOPE_AGENT);
        }
    }
}

// Y = H2_all @ Wout + bout, in place (block stages its 64 rows before writing).
__global__ __launch_bounds__(256) void k_ygemm2(
    float* __restrict__ y, const _Float16* __restrict__ pkY,
    const float* __restrict__ bout)
{
    __shared__ _Float16 Ah[64][264];
    __shared__ _Float16 Al[64][264];
    const size_t m0 = (size_t)blockIdx.x * 64;
    const int tid = threadIdx.x;
    for (int idx = tid; idx < 64 * 256; idx += 256) {
        int r = idx >> 8, k = idx & 255;
        float v = y[(m0 + r) * 1024 + k];
        _Float16 hi = (_Float16)v;
        Ah[r][k] = hi;
        Al[r][k] = (_Float16)((v - (float)hi) * 2048.0f);
    }
    __syncthreads();
    const int wave = tid >> 6, lane = tid & 63;
    const int col = lane & 15, kg = lane >> 4;
    const int ar = wave * 16 + col;
    const size_t orow = m0 + wave * 16 + kg * 4;
    for (int npass = 0; npass < 8; ++npass) {
        f32x4 aA[8], aB[8];
        #pragma unroll
        for (int nt = 0; nt < 8; ++nt) { aA[nt] = (f32x4){0.f,0.f,0.f,0.f}; aB[nt] = aA[nt]; }
        for (int kb = 0; kb < 8; ++kb) {
            h8 ah = *(const h8*)&Ah[ar][kb * 32 + kg * 8];
            h8 al = *(const h8*)&Al[ar][kb * 32 + kg * 8];
            #pragma unroll
            for (int nt = 0; nt < 8; ++nt) {
                const int ngrp = npass * 8 + nt;
                const _Float16* pb = pkY + ((size_t)(ngrp * 8 + kb) * 64 + lane) * 8;
                h8 bh = *(const h8*)pb;
                h8 bl = *(const h8*)(pb + 262144);
                aA[nt] = MFMA16(ah, bh, aA[nt]);
                aB[nt] = MFMA16(ah, bl, aB[nt]);
                aB[nt] = MFMA16(al, bh, aB[nt]);
            }
        }
        #pragma unroll
        for (int nt = 0; nt < 8; ++nt) {
            int n = npass * 128 + nt * 16 + col;
            float bbo = bout[n];
            #pragma unroll
            for (int q = 0; q < 4; ++q)
                y[(orow + q) * 1024 + n] = aA[nt][q] + aB[nt][q] * (1.0f / 2048.0f) + bbo;
        }
    }
}

// ---------------- launch ----------------
extern "C" void kernel_launch(void* const* d_in, const int* in_sizes, int n_in,
                              void* d_out, int out_size, void* d_ws, size_t ws_size,
                              hipStream_t stream) {
    const int*   X    = (const int*)  d_in[0];
    const float* H1in = (const float*)d_in[1];
    const float* C1in = (const float*)d_in[2];
    const float* H2in = (const float*)d_in[3];
    const float* C2in = (const float*)d_in[4];
    const float* W1f = (const float*)d_in[5];  const float* b1f = (const float*)d_in[6];
    const float* W1i = (const float*)d_in[7];  const float* b1i = (const float*)d_in[8];
    const float* W1o = (const float*)d_in[9];  const float* b1o = (const float*)d_in[10];
    const float* W1c = (const float*)d_in[11]; const float* b1c = (const float*)d_in[12];
    const float* W2f = (const float*)d_in[13]; const float* b2f = (const float*)d_in[14];
    const float* W2i = (const float*)d_in[15]; const float* b2i = (const float*)d_in[16];
    const float* W2o = (const float*)d_in[17]; const float* b2o = (const float*)d_in[18];
    const float* W2c = (const float*)d_in[19]; const float* b2c = (const float*)d_in[20];
    const float* Wout = (const float*)d_in[21]; const float* bout = (const float*)d_in[22];

    float* y   = (float*)d_out;
    float* H1t = y + YSZ;
    float* C1t = y + YSZ + 1 * 32768;
    float* H2t = y + YSZ + 2 * 32768;
    float* C2t = y + YSZ + 3 * 32768;

    char* ws = (char*)d_ws;
    _Float16* pk2 = (_Float16*)ws;
    _Float16* pk1 = pk2 + 1048576;
    _Float16* pkY = pk1 + 524288;
    float* bp2 = (float*)(ws + 4194304);
    float* bp1 = bp2 + 1024;
    int* flags  = (int*)(ws + 4194304 + 8192);
    int* flagH1 = flags;            // 512*8
    int* flagH2 = flags + 4096;     // 512*8

    k_prep<<<8200, 256, 0, stream>>>(W1f, W1i, W1o, W1c, W2f, W2i, W2o, W2c, Wout,
                                     b1f, b1i, b1o, b1c, b2f, b2i, b2o, b2c,
                                     pk2, pk1, pkY, bp2, bp1);
    k_zero<<<32, 256, 0, stream>>>(flags);

    k_persist<<<256, 256, 0, stream>>>(X, H1in, C1in, H2in, C2in, y,
                                       H1t, C1t, H2t, C2t,
                                       pk2, pk1, bp2, bp1,
                                       W1f, W1i, W1o, W1c,
                                       flagH1, flagH2);

    k_ygemm2<<<1024, 256, 0, stream>>>(y, pkY, bout);
}

// Round 4
// 6440.448 us; speedup vs baseline: 1.1693x; 1.1693x over previous
//
#include <hip/hip_runtime.h>
#include <math.h>

static constexpr int V  = 1024;
static constexpr int NH = 256;
static constexpr int B  = 128;
static constexpr int T  = 512;
static constexpr size_t BV  = (size_t)B * V;
static constexpr size_t YSZ = (size_t)T * B * V;   // 67,108,864

typedef _Float16 h8 __attribute__((ext_vector_type(8)));
typedef _Float16 h4 __attribute__((ext_vector_type(4)));
typedef float f32x4 __attribute__((ext_vector_type(4)));

#define MFMA16(a, b, c) __builtin_amdgcn_mfma_f32_16x16x32_f16((a), (b), (c), 0, 0, 0)

// Split-f16: x = hi + lo*2^-11, lo pre-scaled by 2048. Dot = hi*hi + (hi*lo + lo*hi)*2^-11.
//
// d_out layout (f32): y[T*B][V], tails: H1[B][NH], C1, H2, C2.
// Recurrence stash: h2(t)->y[t][0:256], h1(t)->y[t][256:512] (overwritten by k_ygemm2).
// c1/c2 live in REGISTERS of their owning block; final values written to tails at t=T-1.
//
// Sync protocol: producers store h via agent-scope relaxed atomic stores
// (write-through to the coherence point), drain via __syncthreads (vmcnt0),
// then tid0 does a RELEASE fetch_add on the step flag. Consumers poll the flag
// with RELAXED loads + s_sleep backoff (caches are clean at kernel start and
// every h address is read exactly once, strictly post-flag -> no stale lines;
// no acquire/invalidate needed).
//
// d_ws: pk2 half[2][64][16][64][8], pk1 half[2][64][8][64][8], pkY half[2][64][8][64][8],
//       bp2 f32[1024], bp1 f32[1024], flagH1 int[512*8], flagH2 int[512*8].

__global__ __launch_bounds__(256) void k_prep(
    const float* __restrict__ W1f, const float* __restrict__ W1i,
    const float* __restrict__ W1o, const float* __restrict__ W1c,
    const float* __restrict__ W2f, const float* __restrict__ W2i,
    const float* __restrict__ W2o, const float* __restrict__ W2c,
    const float* __restrict__ Wout,
    const float* __restrict__ b1f, const float* __restrict__ b1i,
    const float* __restrict__ b1o, const float* __restrict__ b1c,
    const float* __restrict__ b2f, const float* __restrict__ b2i,
    const float* __restrict__ b2o, const float* __restrict__ b2c,
    _Float16* __restrict__ pk2, _Float16* __restrict__ pk1,
    _Float16* __restrict__ pkY, float* __restrict__ bp2, float* __restrict__ bp1)
{
    int idx = blockIdx.x * 256 + threadIdx.x;
    if (idx < 2097152) {
        int KB, e, rowoff = 0;
        bool vocabN = false;
        _Float16* dst;
        if (idx < 1048576)      { e = idx;            KB = 16; dst = pk2; }
        else if (idx < 1572864) { e = idx - 1048576;  KB = 8;  dst = pk1; rowoff = V; }
        else                    { e = idx - 1572864;  KB = 8;  dst = pkY; vocabN = true; }
        int S = 64 * KB * 512;
        int split = e / S, r = e % S;
        int grp = r / (KB * 512);
        int r2  = r % (KB * 512);
        int kb = r2 >> 9, lane = (r2 >> 3) & 63, i = r2 & 7;
        int n = grp * 16 + (lane & 15);
        int k = kb * 32 + (lane >> 4) * 8 + i;
        float val;
        if (vocabN) {
            val = Wout[(size_t)k * 1024 + n];
        } else {
            int j = n >> 2, g = n & 3;
            const float* W = (KB == 16)
                ? (g == 0 ? W2f : g == 1 ? W2i : g == 2 ? W2o : W2c)
                : (g == 0 ? W1f : g == 1 ? W1i : g == 2 ? W1o : W1c);
            val = W[(size_t)(rowoff + k) * NH + j];
        }
        _Float16 hi = (_Float16)val;
        dst[e] = split ? (_Float16)((val - (float)hi) * 2048.0f) : hi;
    } else {
        int bi = idx - 2097152;
        if (bi < 1024) {
            int j = bi >> 2, g = bi & 3;
            bp2[bi] = (g == 0 ? b2f : g == 1 ? b2i : g == 2 ? b2o : b2c)[j];
        } else if (bi < 2048) {
            int b2_ = bi - 1024;
            int j = b2_ >> 2, g = b2_ & 3;
            bp1[b2_] = (g == 0 ? b1f : g == 1 ? b1i : g == 2 ? b1o : b1c)[j];
        }
    }
}

__global__ __launch_bounds__(256) void k_zero(int* __restrict__ flags) {
    flags[blockIdx.x * 256 + threadIdx.x] = 0;
}

__device__ __forceinline__ void waitflag(int* f, int target) {
    while (__hip_atomic_load(f, __ATOMIC_RELAXED, __HIP_MEMORY_SCOPE_AGENT) < target)
        __builtin_amdgcn_s_sleep(1);
}

// Persistent recurrence. 256 blocks: bid<128 -> cell2 role, else cell1 role.
// Block (mp,np) owns rows r0..r0+15, gate-cols np*64..+64 (16 hidden cols), all t.
__global__ __launch_bounds__(256, 1) void k_persist(
    const int* __restrict__ X,
    const float* __restrict__ H1in, const float* __restrict__ C1in,
    const float* __restrict__ H2in, const float* __restrict__ C2in,
    float* __restrict__ y,
    float* __restrict__ H1t, float* __restrict__ C1t,
    float* __restrict__ H2t, float* __restrict__ C2t,
    const _Float16* __restrict__ pk2, const _Float16* __restrict__ pk1,
    const float* __restrict__ bp2, const float* __restrict__ bp1,
    const float* __restrict__ W1f, const float* __restrict__ W1i,
    const float* __restrict__ W1o, const float* __restrict__ W1c,
    int* __restrict__ flagH1, int* __restrict__ flagH2)
{
    const int bid = blockIdx.x, tid = threadIdx.x;
    const bool isC2 = bid < 128;
    const int mp = (bid & 127) >> 4;    // 0..7
    const int np = bid & 15;            // 0..15
    const int r0 = mp * 16;

    __shared__ _Float16 Ah[16][520];
    __shared__ _Float16 Al[16][520];
    __shared__ float    pre[16][64];

    const int wave = tid >> 6, lane = tid & 63;
    const int col = lane & 15, kg = lane >> 4;
    const int KB = isC2 ? 16 : 8;
    const _Float16* pB = (isC2 ? pk2 : pk1) + ((size_t)((np * 4 + wave) * KB * 64) + lane) * 8;
    const size_t so = (size_t)64 * KB * 512;
    const _Float16* arow_h = &Ah[col][kg * 8];
    const _Float16* arow_l = &Al[col][kg * 8];

    const int cr = tid >> 4, cjl = tid & 15;
    const int cb = r0 + cr, cjg = np * 16 + cjl;
    float creg = isC2 ? C2in[cb * NH + cjg] : C1in[cb * NH + cjg];
    const f32x4 bb = *(const f32x4*)&((isC2 ? bp2 : bp1)[np * 64 + cjl * 4]);

    for (int t = 0; t < T; ++t) {
        float w1f_ = 0.f, w1i_ = 0.f, w1o_ = 0.f, w1c_ = 0.f;

        if (isC2) {
            // ---- wait h2(t-1) (usually already set), stage it ----
            if (tid == 0 && t) waitflag(&flagH2[(t - 1) * 8 + mp], 16);
            __syncthreads();
            {
                const float* h2p = t ? (y + (size_t)(t - 1) * BV) : H2in;
                const int h2s = t ? V : NH;
                for (int idx = tid; idx < 16 * 64; idx += 256) {
                    int r = idx >> 6, k4 = idx & 63;
                    f32x4 v = *(const f32x4*)(h2p + (size_t)(r0 + r) * h2s + k4 * 4);
                    h4 hi, lo;
                    #pragma unroll
                    for (int e = 0; e < 4; ++e) {
                        _Float16 h = (_Float16)v[e];
                        hi[e] = h; lo[e] = (_Float16)((v[e] - (float)h) * 2048.0f);
                    }
                    *(h4*)&Ah[r][256 + k4 * 4] = hi;
                    *(h4*)&Al[r][256 + k4 * 4] = lo;
                }
            }
            // ---- wait h1(t), stage it ----
            if (tid == 0) waitflag(&flagH1[t * 8 + mp], 16);
            __syncthreads();
            {
                const float* h1p = y + (size_t)t * BV + 256;
                for (int idx = tid; idx < 16 * 64; idx += 256) {
                    int r = idx >> 6, k4 = idx & 63;
                    f32x4 v = *(const f32x4*)(h1p + (size_t)(r0 + r) * V + k4 * 4);
                    h4 hi, lo;
                    #pragma unroll
                    for (int e = 0; e < 4; ++e) {
                        _Float16 h = (_Float16)v[e];
                        hi[e] = h; lo[e] = (_Float16)((v[e] - (float)h) * 2048.0f);
                    }
                    *(h4*)&Ah[r][k4 * 4] = hi;
                    *(h4*)&Al[r][k4 * 4] = lo;
                }
            }
        } else {
            // ---- wait h1(t-1) ----
            if (tid == 0 && t) waitflag(&flagH1[(t - 1) * 8 + mp], 16);
            __syncthreads();
            // early-issue the token-row gathers (consumed in combine, latency hidden)
            {
                int tok = X[cb * T + t];
                w1f_ = W1f[(size_t)tok * NH + cjg];
                w1i_ = W1i[(size_t)tok * NH + cjg];
                w1o_ = W1o[(size_t)tok * NH + cjg];
                w1c_ = W1c[(size_t)tok * NH + cjg];
            }
            const float* h1p = t ? (y + (size_t)(t - 1) * BV + 256) : H1in;
            const int h1s = t ? V : NH;
            for (int idx = tid; idx < 16 * 64; idx += 256) {
                int r = idx >> 6, k4 = idx & 63;
                f32x4 v = *(const f32x4*)(h1p + (size_t)(r0 + r) * h1s + k4 * 4);
                h4 hi, lo;
                #pragma unroll
                for (int e = 0; e < 4; ++e) {
                    _Float16 h = (_Float16)v[e];
                    hi[e] = h; lo[e] = (_Float16)((v[e] - (float)h) * 2048.0f);
                }
                *(h4*)&Ah[r][k4 * 4] = hi;
                *(h4*)&Al[r][k4 * 4] = lo;
            }
        }
        __syncthreads();

        // ---- MFMA: 16x16 out tile per wave ----
        f32x4 a0 = {0.f, 0.f, 0.f, 0.f}, a1 = a0, a2 = a0;
        for (int kb = 0; kb < KB; ++kb) {
            h8 ah = *(const h8*)(arow_h + kb * 32);
            h8 al = *(const h8*)(arow_l + kb * 32);
            h8 bh = *(const h8*)(pB + (size_t)kb * 512);
            h8 bl = *(const h8*)(pB + so + (size_t)kb * 512);
            a0 = MFMA16(ah, bh, a0);
            a1 = MFMA16(ah, bl, a1);
            a2 = MFMA16(al, bh, a2);
        }
        const int n_local = wave * 16 + col;
        #pragma unroll
        for (int q = 0; q < 4; ++q)
            pre[kg * 4 + q][n_local] = a0[q] + (a1[q] + a2[q]) * (1.0f / 2048.0f);
        __syncthreads();

        // ---- combine gates, update c (register), store h ----
        {
            f32x4 g = *(const f32x4*)&pre[cr][cjl * 4];
            float pf = g[0] + bb[0], pi = g[1] + bb[1], po = g[2] + bb[2], pc = g[3] + bb[3];
            if (!isC2) {
                pf += w1f_; pi += w1i_; po += w1o_; pc += w1c_;
            }
            float fg = 1.f / (1.f + expf(-pf));
            float ig = 1.f / (1.f + expf(-pi));
            float og = 1.f / (1.f + expf(-po));
            float ct = tanhf(pc);
            creg = fmaf(fg, creg, ig * ct);
            float h = og * tanhf(creg);
            size_t dst = (size_t)t * BV + (size_t)cb * V + (isC2 ? 0 : 256) + cjg;
            __hip_atomic_store(&y[dst], h, __ATOMIC_RELAXED, __HIP_MEMORY_SCOPE_AGENT);
            if (t == T - 1) {
                if (isC2) { H2t[cb * NH + cjg] = h; C2t[cb * NH + cjg] = creg; }
                else      { H1t[cb * NH + cjg] = h; C1t[cb * NH + cjg] = creg; }
            }
        }
        __syncthreads();   // drains vmcnt(0): all h stores at agent scope before signal

        if (tid == 0) {
            int* f = (isC2 ? flagH2 : flagH1) + t * 8 + mp;
            __hip_atomic_fetch_add(f, 1, __ATOMIC_RELEASE, __HIP_MEMORY_SCOPE_AGENT);
        }
    }
}

// Y = H2_all @ Wout + bout, in place (block stages its 64 rows before writing).
__global__ __launch_bounds__(256) void k_ygemm2(
    float* __restrict__ y, const _Float16* __restrict__ pkY,
    const float* __restrict__ bout)
{
    __shared__ _Float16 Ah[64][264];
    __shared__ _Float16 Al[64][264];
    const size_t m0 = (size_t)blockIdx.x * 64;
    const int tid = threadIdx.x;
    for (int idx = tid; idx < 64 * 256; idx += 256) {
        int r = idx >> 8, k = idx & 255;
        float v = y[(m0 + r) * 1024 + k];
        _Float16 hi = (_Float16)v;
        Ah[r][k] = hi;
        Al[r][k] = (_Float16)((v - (float)hi) * 2048.0f);
    }
    __syncthreads();
    const int wave = tid >> 6, lane = tid & 63;
    const int col = lane & 15, kg = lane >> 4;
    const int ar = wave * 16 + col;
    const size_t orow = m0 + wave * 16 + kg * 4;
    for (int npass = 0; npass < 8; ++npass) {
        f32x4 aA[8], aB[8];
        #pragma unroll
        for (int nt = 0; nt < 8; ++nt) { aA[nt] = (f32x4){0.f,0.f,0.f,0.f}; aB[nt] = aA[nt]; }
        for (int kb = 0; kb < 8; ++kb) {
            h8 ah = *(const h8*)&Ah[ar][kb * 32 + kg * 8];
            h8 al = *(const h8*)&Al[ar][kb * 32 + kg * 8];
            #pragma unroll
            for (int nt = 0; nt < 8; ++nt) {
                const int ngrp = npass * 8 + nt;
                const _Float16* pb = pkY + ((size_t)(ngrp * 8 + kb) * 64 + lane) * 8;
                h8 bh = *(const h8*)pb;
                h8 bl = *(const h8*)(pb + 262144);
                aA[nt] = MFMA16(ah, bh, aA[nt]);
                aB[nt] = MFMA16(ah, bl, aB[nt]);
                aB[nt] = MFMA16(al, bh, aB[nt]);
            }
        }
        #pragma unroll
        for (int nt = 0; nt < 8; ++nt) {
            int n = npass * 128 + nt * 16 + col;
            float bbo = bout[n];
            #pragma unroll
            for (int q = 0; q < 4; ++q)
                y[(orow + q) * 1024 + n] = aA[nt][q] + aB[nt][q] * (1.0f / 2048.0f) + bbo;
        }
    }
}

// ---------------- launch ----------------
extern "C" void kernel_launch(void* const* d_in, const int* in_sizes, int n_in,
                              void* d_out, int out_size, void* d_ws, size_t ws_size,
                              hipStream_t stream) {
    const int*   X    = (const int*)  d_in[0];
    const float* H1in = (const float*)d_in[1];
    const float* C1in = (const float*)d_in[2];
    const float* H2in = (const float*)d_in[3];
    const float* C2in = (const float*)d_in[4];
    const float* W1f = (const float*)d_in[5];  const float* b1f = (const float*)d_in[6];
    const float* W1i = (const float*)d_in[7];  const float* b1i = (const float*)d_in[8];
    const float* W1o = (const float*)d_in[9];  const float* b1o = (const float*)d_in[10];
    const float* W1c = (const float*)d_in[11]; const float* b1c = (const float*)d_in[12];
    const float* W2f = (const float*)d_in[13]; const float* b2f = (const float*)d_in[14];
    const float* W2i = (const float*)d_in[15]; const float* b2i = (const float*)d_in[16];
    const float* W2o = (const float*)d_in[17]; const float* b2o = (const float*)d_in[18];
    const float* W2c = (const float*)d_in[19]; const float* b2c = (const float*)d_in[20];
    const float* Wout = (const float*)d_in[21]; const float* bout = (const float*)d_in[22];

    float* y   = (float*)d_out;
    float* H1t = y + YSZ;
    float* C1t = y + YSZ + 1 * 32768;
    float* H2t = y + YSZ + 2 * 32768;
    float* C2t = y + YSZ + 3 * 32768;

    char* ws = (char*)d_ws;
    _Float16* pk2 = (_Float16*)ws;
    _Float16* pk1 = pk2 + 1048576;
    _Float16* pkY = pk1 + 524288;
    float* bp2 = (float*)(ws + 4194304);
    float* bp1 = bp2 + 1024;
    int* flags  = (int*)(ws + 4194304 + 8192);
    int* flagH1 = flags;            // 512*8
    int* flagH2 = flags + 4096;     // 512*8

    k_prep<<<8200, 256, 0, stream>>>(W1f, W1i, W1o, W1c, W2f, W2i, W2o, W2c, Wout,
                                     b1f, b1i, b1o, b1c, b2f, b2i, b2o, b2c,
                                     pk2, pk1, pkY, bp2, bp1);
    k_zero<<<32, 256, 0, stream>>>(flags);

    k_persist<<<256, 256, 0, stream>>>(X, H1in, C1in, H2in, C2in, y,
                                       H1t, C1t, H2t, C2t,
                                       pk2, pk1, bp2, bp1,
                                       W1f, W1i, W1o, W1c,
                                       flagH1, flagH2);

    k_ygemm2<<<1024, 256, 0, stream>>>(y, pkY, bout);
}

// Round 5
// 4394.312 us; speedup vs baseline: 1.7137x; 1.4656x over previous
//
#include <hip/hip_runtime.h>
#include <math.h>

static constexpr int V  = 1024;
static constexpr int NH = 256;
static constexpr int B  = 128;
static constexpr int T  = 512;
static constexpr size_t BV  = (size_t)B * V;
static constexpr size_t YSZ = (size_t)T * B * V;   // 67,108,864

typedef _Float16 h8 __attribute__((ext_vector_type(8)));
typedef _Float16 h4 __attribute__((ext_vector_type(4)));
typedef float f32x4 __attribute__((ext_vector_type(4)));

#define MFMA16(a, b, c) __builtin_amdgcn_mfma_f32_16x16x32_f16((a), (b), (c), 0, 0, 0)

// Split-f16: x = hi + lo*2^-11, lo pre-scaled by 2048. Dot = hi*hi + (hi*lo + lo*hi)*2^-11.
//
// d_out layout (f32): y[T*B][V], tails: H1[B][NH], C1, H2, C2.
// Recurrence stash: h2(t)->y[t][0:256], h1(t)->y[t][256:512] (overwritten by k_ygemm2).
// c1/c2 live in registers; B-weights preloaded to registers BEFORE the t-loop.
//
// Sync: per-producer flag WORDS flag[(t*8+mp)*16+np] (release store, no RMW);
// consumer wave0 lanes 0..15 poll the 16-word line with relaxed agent loads,
// __syncthreads orders the rest of the block. Caches: L1/L2 invalidated at
// dispatch start; every y address is written once then read once strictly
// post-flag; producer h stores are agent-scope write-through -> no staleness.
//
// d_ws: pk2 half[2][64][16][64][8] (2MB), pk1 half[2][64][8][64][8] (1MB),
//       pkY half[2][64][8][64][8] (1MB), bp2/bp1 f32[1024] each,
//       flagH1 int[512*8*16] (256KB), flagH2 int[512*8*16] (256KB).

__global__ __launch_bounds__(256) void k_prep(
    const float* __restrict__ W1f, const float* __restrict__ W1i,
    const float* __restrict__ W1o, const float* __restrict__ W1c,
    const float* __restrict__ W2f, const float* __restrict__ W2i,
    const float* __restrict__ W2o, const float* __restrict__ W2c,
    const float* __restrict__ Wout,
    const float* __restrict__ b1f, const float* __restrict__ b1i,
    const float* __restrict__ b1o, const float* __restrict__ b1c,
    const float* __restrict__ b2f, const float* __restrict__ b2i,
    const float* __restrict__ b2o, const float* __restrict__ b2c,
    _Float16* __restrict__ pk2, _Float16* __restrict__ pk1,
    _Float16* __restrict__ pkY, float* __restrict__ bp2, float* __restrict__ bp1)
{
    int idx = blockIdx.x * 256 + threadIdx.x;
    if (idx < 2097152) {
        int KB, e, rowoff = 0;
        bool vocabN = false;
        _Float16* dst;
        if (idx < 1048576)      { e = idx;            KB = 16; dst = pk2; }
        else if (idx < 1572864) { e = idx - 1048576;  KB = 8;  dst = pk1; rowoff = V; }
        else                    { e = idx - 1572864;  KB = 8;  dst = pkY; vocabN = true; }
        int S = 64 * KB * 512;
        int split = e / S, r = e % S;
        int grp = r / (KB * 512);
        int r2  = r % (KB * 512);
        int kb = r2 >> 9, lane = (r2 >> 3) & 63, i = r2 & 7;
        int n = grp * 16 + (lane & 15);
        int k = kb * 32 + (lane >> 4) * 8 + i;
        float val;
        if (vocabN) {
            val = Wout[(size_t)k * 1024 + n];
        } else {
            int j = n >> 2, g = n & 3;
            const float* W = (KB == 16)
                ? (g == 0 ? W2f : g == 1 ? W2i : g == 2 ? W2o : W2c)
                : (g == 0 ? W1f : g == 1 ? W1i : g == 2 ? W1o : W1c);
            val = W[(size_t)(rowoff + k) * NH + j];
        }
        _Float16 hi = (_Float16)val;
        dst[e] = split ? (_Float16)((val - (float)hi) * 2048.0f) : hi;
    } else {
        int bi = idx - 2097152;
        if (bi < 1024) {
            int j = bi >> 2, g = bi & 3;
            bp2[bi] = (g == 0 ? b2f : g == 1 ? b2i : g == 2 ? b2o : b2c)[j];
        } else if (bi < 2048) {
            int b2_ = bi - 1024;
            int j = b2_ >> 2, g = b2_ & 3;
            bp1[b2_] = (g == 0 ? b1f : g == 1 ? b1i : g == 2 ? b1o : b1c)[j];
        }
    }
}

__global__ __launch_bounds__(256) void k_zero(int* __restrict__ flags) {
    flags[blockIdx.x * 256 + threadIdx.x] = 0;
}

// wave0 only: lanes 0..15 poll 16 consecutive flag words (one 64B line)
__device__ __forceinline__ void pollset(int* f16, int lane) {
    for (;;) {
        int v = 1;
        if (lane < 16) v = __hip_atomic_load(&f16[lane], __ATOMIC_RELAXED, __HIP_MEMORY_SCOPE_AGENT);
        if (__all(v != 0)) break;
        __builtin_amdgcn_s_sleep(1);
    }
}

// Persistent recurrence. 256 blocks: bid<128 -> cell2, else cell1.
// Block (mp,np): rows r0..r0+15, gate-cols np*64..+64, all t.
__global__ __launch_bounds__(256, 1) void k_persist(
    const int* __restrict__ X,
    const float* __restrict__ H1in, const float* __restrict__ C1in,
    const float* __restrict__ H2in, const float* __restrict__ C2in,
    float* __restrict__ y,
    float* __restrict__ H1t, float* __restrict__ C1t,
    float* __restrict__ H2t, float* __restrict__ C2t,
    const _Float16* __restrict__ pk2, const _Float16* __restrict__ pk1,
    const float* __restrict__ bp2, const float* __restrict__ bp1,
    const float* __restrict__ W1f, const float* __restrict__ W1i,
    const float* __restrict__ W1o, const float* __restrict__ W1c,
    int* __restrict__ flagH1, int* __restrict__ flagH2)
{
    const int bid = blockIdx.x, tid = threadIdx.x;
    const bool isC2 = bid < 128;
    const int mp = (bid & 127) >> 4;    // 0..7
    const int np = bid & 15;            // 0..15
    const int r0 = mp * 16;

    __shared__ _Float16 Ah[16][520];
    __shared__ _Float16 Al[16][520];
    __shared__ float    pre[16][64];

    const int wave = tid >> 6, lane = tid & 63;
    const int col = lane & 15, kg = lane >> 4;
    const _Float16* arow_h = &Ah[col][kg * 8];
    const _Float16* arow_l = &Al[col][kg * 8];
    const int n_local = wave * 16 + col;

    const int cr = tid >> 4, cjl = tid & 15;
    const int cb = r0 + cr, cjg = np * 16 + cjl;

    if (isC2) {
        // ---- preload B-weights to registers: KB=16 -> 128 VGPR ----
        h8 wbh[16], wbl[16];
        {
            const _Float16* pB = pk2 + ((size_t)((np * 4 + wave) * 16 * 64) + lane) * 8;
            #pragma unroll
            for (int kb = 0; kb < 16; ++kb) {
                wbh[kb] = *(const h8*)(pB + (size_t)kb * 512);
                wbl[kb] = *(const h8*)(pB + 524288 + (size_t)kb * 512);
            }
        }
        float creg = C2in[cb * NH + cjg];
        const f32x4 bb = *(const f32x4*)&bp2[np * 64 + cjl * 4];

        for (int t = 0; t < T; ++t) {
            // wait h2(t-1), stage into cols 256..511
            if (t && wave == 0) pollset(&flagH2[((t - 1) * 8 + mp) * 16], lane);
            __syncthreads();
            {
                const float* h2p = t ? (y + (size_t)(t - 1) * BV) : H2in;
                const int h2s = t ? V : NH;
                for (int idx = tid; idx < 16 * 64; idx += 256) {
                    int r = idx >> 6, k4 = idx & 63;
                    f32x4 v = *(const f32x4*)(h2p + (size_t)(r0 + r) * h2s + k4 * 4);
                    h4 hi, lo;
                    #pragma unroll
                    for (int e = 0; e < 4; ++e) {
                        _Float16 h = (_Float16)v[e];
                        hi[e] = h; lo[e] = (_Float16)((v[e] - (float)h) * 2048.0f);
                    }
                    *(h4*)&Ah[r][256 + k4 * 4] = hi;
                    *(h4*)&Al[r][256 + k4 * 4] = lo;
                }
            }
            // wait h1(t), stage into cols 0..255
            if (wave == 0) pollset(&flagH1[(t * 8 + mp) * 16], lane);
            __syncthreads();
            {
                const float* h1p = y + (size_t)t * BV + 256;
                for (int idx = tid; idx < 16 * 64; idx += 256) {
                    int r = idx >> 6, k4 = idx & 63;
                    f32x4 v = *(const f32x4*)(h1p + (size_t)(r0 + r) * V + k4 * 4);
                    h4 hi, lo;
                    #pragma unroll
                    for (int e = 0; e < 4; ++e) {
                        _Float16 h = (_Float16)v[e];
                        hi[e] = h; lo[e] = (_Float16)((v[e] - (float)h) * 2048.0f);
                    }
                    *(h4*)&Ah[r][k4 * 4] = hi;
                    *(h4*)&Al[r][k4 * 4] = lo;
                }
            }
            __syncthreads();

            f32x4 a0 = {0.f, 0.f, 0.f, 0.f}, a1 = a0, a2 = a0;
            #pragma unroll
            for (int kb = 0; kb < 16; ++kb) {
                h8 ah = *(const h8*)(arow_h + kb * 32);
                h8 al = *(const h8*)(arow_l + kb * 32);
                a0 = MFMA16(ah, wbh[kb], a0);
                a1 = MFMA16(ah, wbl[kb], a1);
                a2 = MFMA16(al, wbh[kb], a2);
            }
            #pragma unroll
            for (int q = 0; q < 4; ++q)
                pre[kg * 4 + q][n_local] = a0[q] + (a1[q] + a2[q]) * (1.0f / 2048.0f);
            __syncthreads();

            {
                f32x4 g = *(const f32x4*)&pre[cr][cjl * 4];
                float pf = g[0] + bb[0], pi = g[1] + bb[1], po = g[2] + bb[2], pc = g[3] + bb[3];
                float fg = 1.f / (1.f + expf(-pf));
                float ig = 1.f / (1.f + expf(-pi));
                float og = 1.f / (1.f + expf(-po));
                float ct = tanhf(pc);
                creg = fmaf(fg, creg, ig * ct);
                float h = og * tanhf(creg);
                __hip_atomic_store(&y[(size_t)t * BV + (size_t)cb * V + cjg], h,
                                   __ATOMIC_RELAXED, __HIP_MEMORY_SCOPE_AGENT);
                if (t == T - 1) { H2t[cb * NH + cjg] = h; C2t[cb * NH + cjg] = creg; }
            }
            __syncthreads();   // vmcnt(0) drain: all h2 stores visible before flag
            if (tid == 0)
                __hip_atomic_store(&flagH2[(t * 8 + mp) * 16 + np], 1,
                                   __ATOMIC_RELEASE, __HIP_MEMORY_SCOPE_AGENT);
        }
    } else {
        // ---- preload B-weights to registers: KB=8 -> 64 VGPR ----
        h8 wbh[8], wbl[8];
        {
            const _Float16* pB = pk1 + ((size_t)((np * 4 + wave) * 8 * 64) + lane) * 8;
            #pragma unroll
            for (int kb = 0; kb < 8; ++kb) {
                wbh[kb] = *(const h8*)(pB + (size_t)kb * 512);
                wbl[kb] = *(const h8*)(pB + 262144 + (size_t)kb * 512);
            }
        }
        float creg = C1in[cb * NH + cjg];
        const f32x4 bb = *(const f32x4*)&bp1[np * 64 + cjl * 4];

        for (int t = 0; t < T; ++t) {
            // early-issue token-row gathers (consumed in combine)
            int tok = X[cb * T + t];
            float w1f_ = W1f[(size_t)tok * NH + cjg];
            float w1i_ = W1i[(size_t)tok * NH + cjg];
            float w1o_ = W1o[(size_t)tok * NH + cjg];
            float w1c_ = W1c[(size_t)tok * NH + cjg];

            if (t && wave == 0) pollset(&flagH1[((t - 1) * 8 + mp) * 16], lane);
            __syncthreads();
            {
                const float* h1p = t ? (y + (size_t)(t - 1) * BV + 256) : H1in;
                const int h1s = t ? V : NH;
                for (int idx = tid; idx < 16 * 64; idx += 256) {
                    int r = idx >> 6, k4 = idx & 63;
                    f32x4 v = *(const f32x4*)(h1p + (size_t)(r0 + r) * h1s + k4 * 4);
                    h4 hi, lo;
                    #pragma unroll
                    for (int e = 0; e < 4; ++e) {
                        _Float16 h = (_Float16)v[e];
                        hi[e] = h; lo[e] = (_Float16)((v[e] - (float)h) * 2048.0f);
                    }
                    *(h4*)&Ah[r][k4 * 4] = hi;
                    *(h4*)&Al[r][k4 * 4] = lo;
                }
            }
            __syncthreads();

            f32x4 a0 = {0.f, 0.f, 0.f, 0.f}, a1 = a0, a2 = a0;
            #pragma unroll
            for (int kb = 0; kb < 8; ++kb) {
                h8 ah = *(const h8*)(arow_h + kb * 32);
                h8 al = *(const h8*)(arow_l + kb * 32);
                a0 = MFMA16(ah, wbh[kb], a0);
                a1 = MFMA16(ah, wbl[kb], a1);
                a2 = MFMA16(al, wbh[kb], a2);
            }
            #pragma unroll
            for (int q = 0; q < 4; ++q)
                pre[kg * 4 + q][n_local] = a0[q] + (a1[q] + a2[q]) * (1.0f / 2048.0f);
            __syncthreads();

            {
                f32x4 g = *(const f32x4*)&pre[cr][cjl * 4];
                float pf = g[0] + bb[0] + w1f_, pi = g[1] + bb[1] + w1i_;
                float po = g[2] + bb[2] + w1o_, pc = g[3] + bb[3] + w1c_;
                float fg = 1.f / (1.f + expf(-pf));
                float ig = 1.f / (1.f + expf(-pi));
                float og = 1.f / (1.f + expf(-po));
                float ct = tanhf(pc);
                creg = fmaf(fg, creg, ig * ct);
                float h = og * tanhf(creg);
                __hip_atomic_store(&y[(size_t)t * BV + (size_t)cb * V + 256 + cjg], h,
                                   __ATOMIC_RELAXED, __HIP_MEMORY_SCOPE_AGENT);
                if (t == T - 1) { H1t[cb * NH + cjg] = h; C1t[cb * NH + cjg] = creg; }
            }
            __syncthreads();
            if (tid == 0)
                __hip_atomic_store(&flagH1[(t * 8 + mp) * 16 + np], 1,
                                   __ATOMIC_RELEASE, __HIP_MEMORY_SCOPE_AGENT);
        }
    }
}

// Y = H2_all @ Wout + bout, in place (block stages its 64 rows before writing).
__global__ __launch_bounds__(256) void k_ygemm2(
    float* __restrict__ y, const _Float16* __restrict__ pkY,
    const float* __restrict__ bout)
{
    __shared__ _Float16 Ah[64][264];
    __shared__ _Float16 Al[64][264];
    const size_t m0 = (size_t)blockIdx.x * 64;
    const int tid = threadIdx.x;
    for (int idx = tid; idx < 64 * 256; idx += 256) {
        int r = idx >> 8, k = idx & 255;
        float v = y[(m0 + r) * 1024 + k];
        _Float16 hi = (_Float16)v;
        Ah[r][k] = hi;
        Al[r][k] = (_Float16)((v - (float)hi) * 2048.0f);
    }
    __syncthreads();
    const int wave = tid >> 6, lane = tid & 63;
    const int col = lane & 15, kg = lane >> 4;
    const int ar = wave * 16 + col;
    const size_t orow = m0 + wave * 16 + kg * 4;
    for (int npass = 0; npass < 8; ++npass) {
        f32x4 aA[8], aB[8];
        #pragma unroll
        for (int nt = 0; nt < 8; ++nt) { aA[nt] = (f32x4){0.f,0.f,0.f,0.f}; aB[nt] = aA[nt]; }
        for (int kb = 0; kb < 8; ++kb) {
            h8 ah = *(const h8*)&Ah[ar][kb * 32 + kg * 8];
            h8 al = *(const h8*)&Al[ar][kb * 32 + kg * 8];
            #pragma unroll
            for (int nt = 0; nt < 8; ++nt) {
                const int ngrp = npass * 8 + nt;
                const _Float16* pb = pkY + ((size_t)(ngrp * 8 + kb) * 64 + lane) * 8;
                h8 bh = *(const h8*)pb;
                h8 bl = *(const h8*)(pb + 262144);
                aA[nt] = MFMA16(ah, bh, aA[nt]);
                aB[nt] = MFMA16(ah, bl, aB[nt]);
                aB[nt] = MFMA16(al, bh, aB[nt]);
            }
        }
        #pragma unroll
        for (int nt = 0; nt < 8; ++nt) {
            int n = npass * 128 + nt * 16 + col;
            float bbo = bout[n];
            #pragma unroll
            for (int q = 0; q < 4; ++q)
                y[(orow + q) * 1024 + n] = aA[nt][q] + aB[nt][q] * (1.0f / 2048.0f) + bbo;
        }
    }
}

// ---------------- launch ----------------
extern "C" void kernel_launch(void* const* d_in, const int* in_sizes, int n_in,
                              void* d_out, int out_size, void* d_ws, size_t ws_size,
                              hipStream_t stream) {
    const int*   X    = (const int*)  d_in[0];
    const float* H1in = (const float*)d_in[1];
    const float* C1in = (const float*)d_in[2];
    const float* H2in = (const float*)d_in[3];
    const float* C2in = (const float*)d_in[4];
    const float* W1f = (const float*)d_in[5];  const float* b1f = (const float*)d_in[6];
    const float* W1i = (const float*)d_in[7];  const float* b1i = (const float*)d_in[8];
    const float* W1o = (const float*)d_in[9];  const float* b1o = (const float*)d_in[10];
    const float* W1c = (const float*)d_in[11]; const float* b1c = (const float*)d_in[12];
    const float* W2f = (const float*)d_in[13]; const float* b2f = (const float*)d_in[14];
    const float* W2i = (const float*)d_in[15]; const float* b2i = (const float*)d_in[16];
    const float* W2o = (const float*)d_in[17]; const float* b2o = (const float*)d_in[18];
    const float* W2c = (const float*)d_in[19]; const float* b2c = (const float*)d_in[20];
    const float* Wout = (const float*)d_in[21]; const float* bout = (const float*)d_in[22];

    float* y   = (float*)d_out;
    float* H1t = y + YSZ;
    float* C1t = y + YSZ + 1 * 32768;
    float* H2t = y + YSZ + 2 * 32768;
    float* C2t = y + YSZ + 3 * 32768;

    char* ws = (char*)d_ws;
    _Float16* pk2 = (_Float16*)ws;
    _Float16* pk1 = pk2 + 1048576;
    _Float16* pkY = pk1 + 524288;
    float* bp2 = (float*)(ws + 4194304);
    float* bp1 = bp2 + 1024;
    int* flags  = (int*)(ws + 4194304 + 8192);
    int* flagH1 = flags;             // 512*8*16
    int* flagH2 = flags + 65536;     // 512*8*16

    k_prep<<<8200, 256, 0, stream>>>(W1f, W1i, W1o, W1c, W2f, W2i, W2o, W2c, Wout,
                                     b1f, b1i, b1o, b1c, b2f, b2i, b2o, b2c,
                                     pk2, pk1, pkY, bp2, bp1);
    k_zero<<<512, 256, 0, stream>>>(flags);

    k_persist<<<256, 256, 0, stream>>>(X, H1in, C1in, H2in, C2in, y,
                                       H1t, C1t, H2t, C2t,
                                       pk2, pk1, bp2, bp1,
                                       W1f, W1i, W1o, W1c,
                                       flagH1, flagH2);

    k_ygemm2<<<1024, 256, 0, stream>>>(y, pkY, bout);
}

// Round 6
// 3216.505 us; speedup vs baseline: 2.3413x; 1.3662x over previous
//
#include <hip/hip_runtime.h>
#include <math.h>

static constexpr int V  = 1024;
static constexpr int NH = 256;
static constexpr int B  = 128;
static constexpr int T  = 512;
static constexpr size_t BV  = (size_t)B * V;
static constexpr size_t YSZ = (size_t)T * B * V;   // 67,108,864
static constexpr unsigned SENT = 0xFFC0DEADu;      // negative NaN payload; h in (-1,1) can never equal it

typedef _Float16 h8 __attribute__((ext_vector_type(8)));
typedef _Float16 h4 __attribute__((ext_vector_type(4)));
typedef float f32x4 __attribute__((ext_vector_type(4)));

#define MFMA16(a, b, c) __builtin_amdgcn_mfma_f32_16x16x32_f16((a), (b), (c), 0, 0, 0)
#define ALOAD(p)  __hip_atomic_load((p),  __ATOMIC_RELAXED, __HIP_MEMORY_SCOPE_AGENT)
#define ASTORE(p, v) __hip_atomic_store((p), (v), __ATOMIC_RELAXED, __HIP_MEMORY_SCOPE_AGENT)

// Split-f16: x = hi + lo*2^-11, lo pre-scaled by 2048. Dot = hi*hi + (hi*lo + lo*hi)*2^-11.
//
// d_out layout (f32): y[T*B][V], tails: H1[B][NH], C1, H2, C2.
// Recurrence stash: h2(t)->y[t][0:256], h1(t)->y[t][256:512] (overwritten by k_ygemm2).
// SYNC = data-as-flag: stash pre-filled with SENT; producers write h via relaxed
// agent write-through atomic stores; consumers poll elements with relaxed agent
// atomic loads until != SENT. One L3 hop on the critical path, no fences.
// c1/c2 in registers; B-weights pinned in registers via asm-opaque trick.
//
// d_ws: pk2 half[2][64][16][64][8] (2MB), pk1 half[2][64][8][64][8] (1MB),
//       pkY half[2][64][8][64][8] (1MB), bp2/bp1 f32[1024] each.

__global__ __launch_bounds__(256) void k_prep(
    const float* __restrict__ W1f, const float* __restrict__ W1i,
    const float* __restrict__ W1o, const float* __restrict__ W1c,
    const float* __restrict__ W2f, const float* __restrict__ W2i,
    const float* __restrict__ W2o, const float* __restrict__ W2c,
    const float* __restrict__ Wout,
    const float* __restrict__ b1f, const float* __restrict__ b1i,
    const float* __restrict__ b1o, const float* __restrict__ b1c,
    const float* __restrict__ b2f, const float* __restrict__ b2i,
    const float* __restrict__ b2o, const float* __restrict__ b2c,
    _Float16* __restrict__ pk2, _Float16* __restrict__ pk1,
    _Float16* __restrict__ pkY, float* __restrict__ bp2, float* __restrict__ bp1)
{
    int idx = blockIdx.x * 256 + threadIdx.x;
    if (idx < 2097152) {
        int KB, e, rowoff = 0;
        bool vocabN = false;
        _Float16* dst;
        if (idx < 1048576)      { e = idx;            KB = 16; dst = pk2; }
        else if (idx < 1572864) { e = idx - 1048576;  KB = 8;  dst = pk1; rowoff = V; }
        else                    { e = idx - 1572864;  KB = 8;  dst = pkY; vocabN = true; }
        int S = 64 * KB * 512;
        int split = e / S, r = e % S;
        int grp = r / (KB * 512);
        int r2  = r % (KB * 512);
        int kb = r2 >> 9, lane = (r2 >> 3) & 63, i = r2 & 7;
        int n = grp * 16 + (lane & 15);
        int k = kb * 32 + (lane >> 4) * 8 + i;
        float val;
        if (vocabN) {
            val = Wout[(size_t)k * 1024 + n];
        } else {
            int j = n >> 2, g = n & 3;
            const float* W = (KB == 16)
                ? (g == 0 ? W2f : g == 1 ? W2i : g == 2 ? W2o : W2c)
                : (g == 0 ? W1f : g == 1 ? W1i : g == 2 ? W1o : W1c);
            val = W[(size_t)(rowoff + k) * NH + j];
        }
        _Float16 hi = (_Float16)val;
        dst[e] = split ? (_Float16)((val - (float)hi) * 2048.0f) : hi;
    } else {
        int bi = idx - 2097152;
        if (bi < 1024) {
            int j = bi >> 2, g = bi & 3;
            bp2[bi] = (g == 0 ? b2f : g == 1 ? b2i : g == 2 ? b2o : b2c)[j];
        } else if (bi < 2048) {
            int b2_ = bi - 1024;
            int j = b2_ >> 2, g = b2_ & 3;
            bp1[b2_] = (g == 0 ? b1f : g == 1 ? b1i : g == 2 ? b1o : b1c)[j];
        }
    }
}

// Fill h-stash (cols 0..511 of every y row) with sentinel. 8,388,608 f32x4 stores.
__global__ __launch_bounds__(256) void k_sent(float* __restrict__ y) {
    const float s = __uint_as_float(SENT);
    const f32x4 sv = {s, s, s, s};
    int gid = blockIdx.x * 256 + threadIdx.x;       // 524288 threads
    for (int n = gid; n < 8388608; n += 524288) {
        int row = n >> 7, c4 = n & 127;
        *(f32x4*)&y[(size_t)row * V + c4 * 4] = sv;
    }
}

__device__ __forceinline__ float pollval(float* p) {
    float v = ALOAD(p);
    while (__float_as_uint(v) == SENT) { __builtin_amdgcn_s_sleep(1); v = ALOAD(p); }
    return v;
}

// Persistent recurrence. 256 blocks: bid<128 -> cell2, else cell1.
// Block (mp,np): rows r0..r0+15, gate-cols np*64..+64, all t.
__global__ __launch_bounds__(256, 1) void k_persist(
    const int* __restrict__ X,
    const float* __restrict__ H1in, const float* __restrict__ C1in,
    const float* __restrict__ H2in, const float* __restrict__ C2in,
    float* __restrict__ y,
    float* __restrict__ H1t, float* __restrict__ C1t,
    float* __restrict__ H2t, float* __restrict__ C2t,
    const _Float16* __restrict__ pk2, const _Float16* __restrict__ pk1,
    const float* __restrict__ bp2, const float* __restrict__ bp1,
    const float* __restrict__ W1f, const float* __restrict__ W1i,
    const float* __restrict__ W1o, const float* __restrict__ W1c)
{
    const int bid = blockIdx.x, tid = threadIdx.x;
    const bool isC2 = bid < 128;
    const int mp = (bid & 127) >> 4;    // 0..7
    const int np = bid & 15;            // 0..15
    const int r0 = mp * 16;

    __shared__ _Float16 Ah[16][520];
    __shared__ _Float16 Al[16][520];
    __shared__ float    pre[16][64];

    const int wave = tid >> 6, lane = tid & 63;
    const int col = lane & 15, kg = lane >> 4;
    const _Float16* arow_h = &Ah[col][kg * 8];
    const _Float16* arow_l = &Al[col][kg * 8];
    const int n_local = wave * 16 + col;

    const int cr = tid >> 4, cjl = tid & 15;
    const int cb = r0 + cr, cjg = np * 16 + cjl;

    // staging element ownership: 4 groups of (row r, 4-col k4)
    const int sr = tid >> 6;            // +g*4 per group
    const int sk4 = tid & 63;

    if (isC2) {
        // ---- preload + PIN B-weights in registers: 128 VGPR ----
        h8 wbh[16], wbl[16];
        {
            const _Float16* pB = pk2 + ((size_t)((np * 4 + wave) * 16 * 64) + lane) * 8;
            #pragma unroll
            for (int kb = 0; kb < 16; ++kb) {
                wbh[kb] = *(const h8*)(pB + (size_t)kb * 512);
                wbl[kb] = *(const h8*)(pB + 524288 + (size_t)kb * 512);
            }
            #pragma unroll
            for (int kb = 0; kb < 16; ++kb)
                asm volatile("" : "+v"(wbh[kb]), "+v"(wbl[kb]));
        }
        float creg = C2in[cb * NH + cjg];
        const f32x4 bb = *(const f32x4*)&bp2[np * 64 + cjl * 4];

        for (int t = 0; t < T; ++t) {
            // ---- poll+stage h2(t-1) -> cols 256..511 ----
            #pragma unroll
            for (int g = 0; g < 4; ++g) {
                const int r = g * 4 + sr;
                float u[4];
                if (t) {
                    float* s = y + (size_t)(t - 1) * BV + (size_t)(r0 + r) * V + sk4 * 4;
                    #pragma unroll
                    for (int e = 0; e < 4; ++e) u[e] = ALOAD(s + e);
                    #pragma unroll
                    for (int e = 0; e < 4; ++e)
                        while (__float_as_uint(u[e]) == SENT) { __builtin_amdgcn_s_sleep(1); u[e] = ALOAD(s + e); }
                } else {
                    const float* s = H2in + (size_t)(r0 + r) * NH + sk4 * 4;
                    #pragma unroll
                    for (int e = 0; e < 4; ++e) u[e] = s[e];
                }
                h4 hi, lo;
                #pragma unroll
                for (int e = 0; e < 4; ++e) {
                    _Float16 h = (_Float16)u[e];
                    hi[e] = h; lo[e] = (_Float16)((u[e] - (float)h) * 2048.0f);
                }
                *(h4*)&Ah[r][256 + sk4 * 4] = hi;
                *(h4*)&Al[r][256 + sk4 * 4] = lo;
            }
            // ---- poll+stage h1(t) -> cols 0..255 ----
            #pragma unroll
            for (int g = 0; g < 4; ++g) {
                const int r = g * 4 + sr;
                float* s = y + (size_t)t * BV + (size_t)(r0 + r) * V + 256 + sk4 * 4;
                float u[4];
                #pragma unroll
                for (int e = 0; e < 4; ++e) u[e] = ALOAD(s + e);
                #pragma unroll
                for (int e = 0; e < 4; ++e)
                    while (__float_as_uint(u[e]) == SENT) { __builtin_amdgcn_s_sleep(1); u[e] = ALOAD(s + e); }
                h4 hi, lo;
                #pragma unroll
                for (int e = 0; e < 4; ++e) {
                    _Float16 h = (_Float16)u[e];
                    hi[e] = h; lo[e] = (_Float16)((u[e] - (float)h) * 2048.0f);
                }
                *(h4*)&Ah[r][sk4 * 4] = hi;
                *(h4*)&Al[r][sk4 * 4] = lo;
            }
            __syncthreads();

            f32x4 a0 = {0.f, 0.f, 0.f, 0.f}, a1 = a0, a2 = a0;
            #pragma unroll
            for (int kb = 0; kb < 16; ++kb) {
                h8 ah = *(const h8*)(arow_h + kb * 32);
                h8 al = *(const h8*)(arow_l + kb * 32);
                a0 = MFMA16(ah, wbh[kb], a0);
                a1 = MFMA16(ah, wbl[kb], a1);
                a2 = MFMA16(al, wbh[kb], a2);
            }
            #pragma unroll
            for (int q = 0; q < 4; ++q)
                pre[kg * 4 + q][n_local] = a0[q] + (a1[q] + a2[q]) * (1.0f / 2048.0f);
            __syncthreads();

            {
                f32x4 g = *(const f32x4*)&pre[cr][cjl * 4];
                float pf = g[0] + bb[0], pi = g[1] + bb[1], po = g[2] + bb[2], pc = g[3] + bb[3];
                float fg = 1.f / (1.f + expf(-pf));
                float ig = 1.f / (1.f + expf(-pi));
                float og = 1.f / (1.f + expf(-po));
                float ct = tanhf(pc);
                creg = fmaf(fg, creg, ig * ct);
                float h = og * tanhf(creg);
                ASTORE(&y[(size_t)t * BV + (size_t)cb * V + cjg], h);
                if (t == T - 1) { H2t[cb * NH + cjg] = h; C2t[cb * NH + cjg] = creg; }
            }
            // no end-of-step barrier needed: staging at t+1 doesn't touch pre[][]
        }
    } else {
        // ---- preload + PIN B-weights: 64 VGPR ----
        h8 wbh[8], wbl[8];
        {
            const _Float16* pB = pk1 + ((size_t)((np * 4 + wave) * 8 * 64) + lane) * 8;
            #pragma unroll
            for (int kb = 0; kb < 8; ++kb) {
                wbh[kb] = *(const h8*)(pB + (size_t)kb * 512);
                wbl[kb] = *(const h8*)(pB + 262144 + (size_t)kb * 512);
            }
            #pragma unroll
            for (int kb = 0; kb < 8; ++kb)
                asm volatile("" : "+v"(wbh[kb]), "+v"(wbl[kb]));
        }
        float creg = C1in[cb * NH + cjg];
        const f32x4 bb = *(const f32x4*)&bp1[np * 64 + cjl * 4];

        for (int t = 0; t < T; ++t) {
            // early-issue token-row gathers (consumed in combine)
            int tok = X[cb * T + t];
            float w1f_ = W1f[(size_t)tok * NH + cjg];
            float w1i_ = W1i[(size_t)tok * NH + cjg];
            float w1o_ = W1o[(size_t)tok * NH + cjg];
            float w1c_ = W1c[(size_t)tok * NH + cjg];

            // ---- poll+stage h1(t-1) -> cols 0..255 ----
            #pragma unroll
            for (int g = 0; g < 4; ++g) {
                const int r = g * 4 + sr;
                float u[4];
                if (t) {
                    float* s = y + (size_t)(t - 1) * BV + (size_t)(r0 + r) * V + 256 + sk4 * 4;
                    #pragma unroll
                    for (int e = 0; e < 4; ++e) u[e] = ALOAD(s + e);
                    #pragma unroll
                    for (int e = 0; e < 4; ++e)
                        while (__float_as_uint(u[e]) == SENT) { __builtin_amdgcn_s_sleep(1); u[e] = ALOAD(s + e); }
                } else {
                    const float* s = H1in + (size_t)(r0 + r) * NH + sk4 * 4;
                    #pragma unroll
                    for (int e = 0; e < 4; ++e) u[e] = s[e];
                }
                h4 hi, lo;
                #pragma unroll
                for (int e = 0; e < 4; ++e) {
                    _Float16 h = (_Float16)u[e];
                    hi[e] = h; lo[e] = (_Float16)((u[e] - (float)h) * 2048.0f);
                }
                *(h4*)&Ah[r][sk4 * 4] = hi;
                *(h4*)&Al[r][sk4 * 4] = lo;
            }
            __syncthreads();

            f32x4 a0 = {0.f, 0.f, 0.f, 0.f}, a1 = a0, a2 = a0;
            #pragma unroll
            for (int kb = 0; kb < 8; ++kb) {
                h8 ah = *(const h8*)(arow_h + kb * 32);
                h8 al = *(const h8*)(arow_l + kb * 32);
                a0 = MFMA16(ah, wbh[kb], a0);
                a1 = MFMA16(ah, wbl[kb], a1);
                a2 = MFMA16(al, wbh[kb], a2);
            }
            #pragma unroll
            for (int q = 0; q < 4; ++q)
                pre[kg * 4 + q][n_local] = a0[q] + (a1[q] + a2[q]) * (1.0f / 2048.0f);
            __syncthreads();

            {
                f32x4 g = *(const f32x4*)&pre[cr][cjl * 4];
                float pf = g[0] + bb[0] + w1f_, pi = g[1] + bb[1] + w1i_;
                float po = g[2] + bb[2] + w1o_, pc = g[3] + bb[3] + w1c_;
                float fg = 1.f / (1.f + expf(-pf));
                float ig = 1.f / (1.f + expf(-pi));
                float og = 1.f / (1.f + expf(-po));
                float ct = tanhf(pc);
                creg = fmaf(fg, creg, ig * ct);
                float h = og * tanhf(creg);
                ASTORE(&y[(size_t)t * BV + (size_t)cb * V + 256 + cjg], h);
                if (t == T - 1) { H1t[cb * NH + cjg] = h; C1t[cb * NH + cjg] = creg; }
            }
        }
    }
}

// Y = H2_all @ Wout + bout, in place (block stages its 64 rows before writing).
__global__ __launch_bounds__(256) void k_ygemm2(
    float* __restrict__ y, const _Float16* __restrict__ pkY,
    const float* __restrict__ bout)
{
    __shared__ _Float16 Ah[64][264];
    __shared__ _Float16 Al[64][264];
    const size_t m0 = (size_t)blockIdx.x * 64;
    const int tid = threadIdx.x;
    for (int idx = tid; idx < 64 * 256; idx += 256) {
        int r = idx >> 8, k = idx & 255;
        float v = y[(m0 + r) * 1024 + k];
        _Float16 hi = (_Float16)v;
        Ah[r][k] = hi;
        Al[r][k] = (_Float16)((v - (float)hi) * 2048.0f);
    }
    __syncthreads();
    const int wave = tid >> 6, lane = tid & 63;
    const int col = lane & 15, kg = lane >> 4;
    const int ar = wave * 16 + col;
    const size_t orow = m0 + wave * 16 + kg * 4;
    for (int npass = 0; npass < 8; ++npass) {
        f32x4 aA[8], aB[8];
        #pragma unroll
        for (int nt = 0; nt < 8; ++nt) { aA[nt] = (f32x4){0.f,0.f,0.f,0.f}; aB[nt] = aA[nt]; }
        for (int kb = 0; kb < 8; ++kb) {
            h8 ah = *(const h8*)&Ah[ar][kb * 32 + kg * 8];
            h8 al = *(const h8*)&Al[ar][kb * 32 + kg * 8];
            #pragma unroll
            for (int nt = 0; nt < 8; ++nt) {
                const int ngrp = npass * 8 + nt;
                const _Float16* pb = pkY + ((size_t)(ngrp * 8 + kb) * 64 + lane) * 8;
                h8 bh = *(const h8*)pb;
                h8 bl = *(const h8*)(pb + 262144);
                aA[nt] = MFMA16(ah, bh, aA[nt]);
                aB[nt] = MFMA16(ah, bl, aB[nt]);
                aB[nt] = MFMA16(al, bh, aB[nt]);
            }
        }
        #pragma unroll
        for (int nt = 0; nt < 8; ++nt) {
            int n = npass * 128 + nt * 16 + col;
            float bbo = bout[n];
            #pragma unroll
            for (int q = 0; q < 4; ++q)
                y[(orow + q) * 1024 + n] = aA[nt][q] + aB[nt][q] * (1.0f / 2048.0f) + bbo;
        }
    }
}

// ---------------- launch ----------------
extern "C" void kernel_launch(void* const* d_in, const int* in_sizes, int n_in,
                              void* d_out, int out_size, void* d_ws, size_t ws_size,
                              hipStream_t stream) {
    const int*   X    = (const int*)  d_in[0];
    const float* H1in = (const float*)d_in[1];
    const float* C1in = (const float*)d_in[2];
    const float* H2in = (const float*)d_in[3];
    const float* C2in = (const float*)d_in[4];
    const float* W1f = (const float*)d_in[5];  const float* b1f = (const float*)d_in[6];
    const float* W1i = (const float*)d_in[7];  const float* b1i = (const float*)d_in[8];
    const float* W1o = (const float*)d_in[9];  const float* b1o = (const float*)d_in[10];
    const float* W1c = (const float*)d_in[11]; const float* b1c = (const float*)d_in[12];
    const float* W2f = (const float*)d_in[13]; const float* b2f = (const float*)d_in[14];
    const float* W2i = (const float*)d_in[15]; const float* b2i = (const float*)d_in[16];
    const float* W2o = (const float*)d_in[17]; const float* b2o = (const float*)d_in[18];
    const float* W2c = (const float*)d_in[19]; const float* b2c = (const float*)d_in[20];
    const float* Wout = (const float*)d_in[21]; const float* bout = (const float*)d_in[22];

    float* y   = (float*)d_out;
    float* H1t = y + YSZ;
    float* C1t = y + YSZ + 1 * 32768;
    float* H2t = y + YSZ + 2 * 32768;
    float* C2t = y + YSZ + 3 * 32768;

    char* ws = (char*)d_ws;
    _Float16* pk2 = (_Float16*)ws;
    _Float16* pk1 = pk2 + 1048576;
    _Float16* pkY = pk1 + 524288;
    float* bp2 = (float*)(ws + 4194304);
    float* bp1 = bp2 + 1024;

    k_prep<<<8200, 256, 0, stream>>>(W1f, W1i, W1o, W1c, W2f, W2i, W2o, W2c, Wout,
                                     b1f, b1i, b1o, b1c, b2f, b2i, b2o, b2c,
                                     pk2, pk1, pkY, bp2, bp1);
    k_sent<<<2048, 256, 0, stream>>>(y);

    k_persist<<<256, 256, 0, stream>>>(X, H1in, C1in, H2in, C2in, y,
                                       H1t, C1t, H2t, C2t,
                                       pk2, pk1, bp2, bp1,
                                       W1f, W1i, W1o, W1c);

    k_ygemm2<<<1024, 256, 0, stream>>>(y, pkY, bout);
}

// Round 7
// 2739.246 us; speedup vs baseline: 2.7492x; 1.1742x over previous
//
#include <hip/hip_runtime.h>
#include <math.h>

static constexpr int V  = 1024;
static constexpr int NH = 256;
static constexpr int B  = 128;
static constexpr int T  = 512;
static constexpr size_t BV  = (size_t)B * V;
static constexpr size_t YSZ = (size_t)T * B * V;   // 67,108,864
static constexpr unsigned SENT = 0xFFC0DEADu;      // NaN payload; h in (-1,1) never equals it

typedef _Float16 h8 __attribute__((ext_vector_type(8)));
typedef _Float16 h4 __attribute__((ext_vector_type(4)));
typedef float f32x4 __attribute__((ext_vector_type(4)));

#define MFMA16(a, b, c) __builtin_amdgcn_mfma_f32_16x16x32_f16((a), (b), (c), 0, 0, 0)
#define ALOAD(p)  __hip_atomic_load((p),  __ATOMIC_RELAXED, __HIP_MEMORY_SCOPE_AGENT)
#define ASTORE(p, v) __hip_atomic_store((p), (v), __ATOMIC_RELAXED, __HIP_MEMORY_SCOPE_AGENT)

// Split-f16: x = hi + lo*2^-11, lo pre-scaled by 2048. Dot = hi*hi + (hi*lo + lo*hi)*2^-11.
// d_out layout (f32): y[T*B][V], tails: H1, C1, H2, C2 (each B*NH).
// Stash: h2(t)->y[t][0:256], h1(t)->y[t][256:512]; sync = data-as-flag (SENT sentinel),
// relaxed agent atomics both sides, one L3 hop.
// k_persist: 256 blocks x 512 threads (8 waves = 4 n-quarters x 2 K-halves).
// Weights register-resident per wave (64 VGPR cell2 / 32 VGPR cell1), pinned via asm.

__global__ __launch_bounds__(256) void k_prep(
    const float* __restrict__ W1f, const float* __restrict__ W1i,
    const float* __restrict__ W1o, const float* __restrict__ W1c,
    const float* __restrict__ W2f, const float* __restrict__ W2i,
    const float* __restrict__ W2o, const float* __restrict__ W2c,
    const float* __restrict__ Wout,
    const float* __restrict__ b1f, const float* __restrict__ b1i,
    const float* __restrict__ b1o, const float* __restrict__ b1c,
    const float* __restrict__ b2f, const float* __restrict__ b2i,
    const float* __restrict__ b2o, const float* __restrict__ b2c,
    _Float16* __restrict__ pk2, _Float16* __restrict__ pk1,
    _Float16* __restrict__ pkY, float* __restrict__ bp2, float* __restrict__ bp1)
{
    int idx = blockIdx.x * 256 + threadIdx.x;
    if (idx < 2097152) {
        int KB, e, rowoff = 0;
        bool vocabN = false;
        _Float16* dst;
        if (idx < 1048576)      { e = idx;            KB = 16; dst = pk2; }
        else if (idx < 1572864) { e = idx - 1048576;  KB = 8;  dst = pk1; rowoff = V; }
        else                    { e = idx - 1572864;  KB = 8;  dst = pkY; vocabN = true; }
        int S = 64 * KB * 512;
        int split = e / S, r = e % S;
        int grp = r / (KB * 512);
        int r2  = r % (KB * 512);
        int kb = r2 >> 9, lane = (r2 >> 3) & 63, i = r2 & 7;
        int n = grp * 16 + (lane & 15);
        int k = kb * 32 + (lane >> 4) * 8 + i;
        float val;
        if (vocabN) {
            val = Wout[(size_t)k * 1024 + n];
        } else {
            int j = n >> 2, g = n & 3;
            const float* W = (KB == 16)
                ? (g == 0 ? W2f : g == 1 ? W2i : g == 2 ? W2o : W2c)
                : (g == 0 ? W1f : g == 1 ? W1i : g == 2 ? W1o : W1c);
            val = W[(size_t)(rowoff + k) * NH + j];
        }
        _Float16 hi = (_Float16)val;
        dst[e] = split ? (_Float16)((val - (float)hi) * 2048.0f) : hi;
    } else {
        int bi = idx - 2097152;
        if (bi < 1024) {
            int j = bi >> 2, g = bi & 3;
            bp2[bi] = (g == 0 ? b2f : g == 1 ? b2i : g == 2 ? b2o : b2c)[j];
        } else if (bi < 2048) {
            int b2_ = bi - 1024;
            int j = b2_ >> 2, g = b2_ & 3;
            bp1[b2_] = (g == 0 ? b1f : g == 1 ? b1i : g == 2 ? b1o : b1c)[j];
        }
    }
}

// Fill h-stash (cols 0..511 of every y row) with sentinel.
__global__ __launch_bounds__(256) void k_sent(float* __restrict__ y) {
    const float s = __uint_as_float(SENT);
    const f32x4 sv = {s, s, s, s};
    int gid = blockIdx.x * 256 + threadIdx.x;       // 524288 threads
    for (int n = gid; n < 8388608; n += 524288) {
        int row = n >> 7, c4 = n & 127;
        *(f32x4*)&y[(size_t)row * V + c4 * 4] = sv;
    }
}

__device__ __forceinline__ void poll4(const float* s, float* u) {
    #pragma unroll
    for (int e = 0; e < 4; ++e) u[e] = ALOAD(s + e);
    #pragma unroll
    for (int e = 0; e < 4; ++e)
        while (__float_as_uint(u[e]) == SENT) { __builtin_amdgcn_s_sleep(1); u[e] = ALOAD(s + e); }
}

__device__ __forceinline__ void cvt4(const float* u, h4* hi4, h4* lo4) {
    h4 hi, lo;
    #pragma unroll
    for (int e = 0; e < 4; ++e) {
        _Float16 h = (_Float16)u[e];
        hi[e] = h; lo[e] = (_Float16)((u[e] - (float)h) * 2048.0f);
    }
    *hi4 = hi; *lo4 = lo;
}

// Persistent recurrence. 256 blocks x 512 thr: bid<128 -> cell2, else cell1.
// Block (mp,np): rows r0..r0+15, gate-cols np*64..+64, all t.
// Wave w: wq=w&3 (16-col group np*4+wq), kh=w>>2 (K-half).
__global__ __launch_bounds__(512, 1) void k_persist(
    const int* __restrict__ X,
    const float* __restrict__ H1in, const float* __restrict__ C1in,
    const float* __restrict__ H2in, const float* __restrict__ C2in,
    float* __restrict__ y,
    float* __restrict__ H1t, float* __restrict__ C1t,
    float* __restrict__ H2t, float* __restrict__ C2t,
    const _Float16* __restrict__ pk2, const _Float16* __restrict__ pk1,
    const float* __restrict__ bp2, const float* __restrict__ bp1,
    const float* __restrict__ W1f, const float* __restrict__ W1i,
    const float* __restrict__ W1o, const float* __restrict__ W1c)
{
    const int bid = blockIdx.x, tid = threadIdx.x;
    const bool isC2 = bid < 128;
    const int mp = (bid & 127) >> 4;    // 0..7
    const int np = bid & 15;            // 0..15
    const int r0 = mp * 16;

    __shared__ _Float16 Ah[16][520];
    __shared__ _Float16 Al[16][520];
    __shared__ float    preA[16][64];
    __shared__ float    preB[16][64];

    const int wave = tid >> 6, lane = tid & 63;
    const int wq = wave & 3, kh = wave >> 2;
    const int col = lane & 15, kg = lane >> 4;
    const _Float16* arow_h = &Ah[col][kg * 8];
    const _Float16* arow_l = &Al[col][kg * 8];
    const int n_local = wq * 16 + col;

    // combine ownership (threads 0..255 only)
    const int cr = tid >> 4, cjl = tid & 15;
    const int cb = r0 + (cr & 15), cjg = np * 16 + cjl;

    if (isC2) {
        // ---- per-wave weights: kb = kh*8 + kb8, 16 h8 = 64 VGPR ----
        h8 wh[8], wl[8];
        {
            const _Float16* pB = pk2 + ((size_t)((np * 4 + wq) * 16 + kh * 8) * 64 + lane) * 8;
            #pragma unroll
            for (int kb8 = 0; kb8 < 8; ++kb8) {
                wh[kb8] = *(const h8*)(pB + (size_t)kb8 * 512);
                wl[kb8] = *(const h8*)(pB + 524288 + (size_t)kb8 * 512);
            }
            #pragma unroll
            for (int kb8 = 0; kb8 < 8; ++kb8)
                asm volatile("" : "+v"(wh[kb8]), "+v"(wl[kb8]));
        }
        float creg = (tid < 256) ? C2in[cb * NH + cjg] : 0.f;
        const f32x4 bb = *(const f32x4*)&bp2[np * 64 + cjl * 4];

        // staging: 16 rows x 128 col4-groups; thread -> sk4 = tid&127, rows srb, srb+4, ...
        const int sk4 = tid & 127;
        const int srb = tid >> 7;   // 0..3

        for (int t = 0; t < T; ++t) {
            #pragma unroll
            for (int g = 0; g < 4; ++g) {
                const int r = g * 4 + srb;
                float u[4];
                if (sk4 < 64) {
                    // h1(t): always polled from y
                    poll4(y + (size_t)t * BV + (size_t)(r0 + r) * V + 256 + sk4 * 4, u);
                } else if (t) {
                    poll4(y + (size_t)(t - 1) * BV + (size_t)(r0 + r) * V + (sk4 - 64) * 4, u);
                } else {
                    const float* s = H2in + (size_t)(r0 + r) * NH + (sk4 - 64) * 4;
                    #pragma unroll
                    for (int e = 0; e < 4; ++e) u[e] = s[e];
                }
                cvt4(u, (h4*)&Ah[r][sk4 * 4], (h4*)&Al[r][sk4 * 4]);
            }
            __syncthreads();

            f32x4 a0 = {0.f, 0.f, 0.f, 0.f}, a1 = a0, a2 = a0;
            #pragma unroll
            for (int kb8 = 0; kb8 < 8; ++kb8) {
                const int kbg = kh * 8 + kb8;
                h8 ah = *(const h8*)(arow_h + kbg * 32);
                h8 al = *(const h8*)(arow_l + kbg * 32);
                a0 = MFMA16(ah, wh[kb8], a0);
                a1 = MFMA16(ah, wl[kb8], a1);
                a2 = MFMA16(al, wh[kb8], a2);
            }
            float* pre = kh ? &preB[0][0] : &preA[0][0];
            #pragma unroll
            for (int q = 0; q < 4; ++q)
                pre[(kg * 4 + q) * 64 + n_local] = a0[q] + (a1[q] + a2[q]) * (1.0f / 2048.0f);
            __syncthreads();

            if (tid < 256) {
                f32x4 gA = *(const f32x4*)&preA[cr][cjl * 4];
                f32x4 gB = *(const f32x4*)&preB[cr][cjl * 4];
                float pf = gA[0] + gB[0] + bb[0], pi = gA[1] + gB[1] + bb[1];
                float po = gA[2] + gB[2] + bb[2], pc = gA[3] + gB[3] + bb[3];
                float fg = 1.f / (1.f + expf(-pf));
                float ig = 1.f / (1.f + expf(-pi));
                float og = 1.f / (1.f + expf(-po));
                float ct = tanhf(pc);
                creg = fmaf(fg, creg, ig * ct);
                float h = og * tanhf(creg);
                ASTORE(&y[(size_t)t * BV + (size_t)cb * V + cjg], h);
                if (t == T - 1) { H2t[cb * NH + cjg] = h; C2t[cb * NH + cjg] = creg; }
            }
        }
    } else {
        // ---- per-wave weights: kb = kh*4 + kb4, 8 h8 = 32 VGPR ----
        h8 wh[4], wl[4];
        {
            const _Float16* pB = pk1 + ((size_t)((np * 4 + wq) * 8 + kh * 4) * 64 + lane) * 8;
            #pragma unroll
            for (int kb4 = 0; kb4 < 4; ++kb4) {
                wh[kb4] = *(const h8*)(pB + (size_t)kb4 * 512);
                wl[kb4] = *(const h8*)(pB + 262144 + (size_t)kb4 * 512);
            }
            #pragma unroll
            for (int kb4 = 0; kb4 < 4; ++kb4)
                asm volatile("" : "+v"(wh[kb4]), "+v"(wl[kb4]));
        }
        float creg = (tid < 256) ? C1in[cb * NH + cjg] : 0.f;
        const f32x4 bb = *(const f32x4*)&bp1[np * 64 + cjl * 4];

        // staging: 16 rows x 64 col4-groups; sk4 = tid&63, rows srb, srb+8
        const int sk4 = tid & 63;
        const int srb = tid >> 6;   // 0..7

        for (int t = 0; t < T; ++t) {
            float w1f_ = 0.f, w1i_ = 0.f, w1o_ = 0.f, w1c_ = 0.f;
            if (tid < 256) {
                int tok = X[cb * T + t];
                w1f_ = W1f[(size_t)tok * NH + cjg];
                w1i_ = W1i[(size_t)tok * NH + cjg];
                w1o_ = W1o[(size_t)tok * NH + cjg];
                w1c_ = W1c[(size_t)tok * NH + cjg];
            }
            #pragma unroll
            for (int g = 0; g < 2; ++g) {
                const int r = g * 8 + srb;
                float u[4];
                if (t) {
                    poll4(y + (size_t)(t - 1) * BV + (size_t)(r0 + r) * V + 256 + sk4 * 4, u);
                } else {
                    const float* s = H1in + (size_t)(r0 + r) * NH + sk4 * 4;
                    #pragma unroll
                    for (int e = 0; e < 4; ++e) u[e] = s[e];
                }
                cvt4(u, (h4*)&Ah[r][sk4 * 4], (h4*)&Al[r][sk4 * 4]);
            }
            __syncthreads();

            f32x4 a0 = {0.f, 0.f, 0.f, 0.f}, a1 = a0, a2 = a0;
            #pragma unroll
            for (int kb4 = 0; kb4 < 4; ++kb4) {
                const int kbg = kh * 4 + kb4;
                h8 ah = *(const h8*)(arow_h + kbg * 32);
                h8 al = *(const h8*)(arow_l + kbg * 32);
                a0 = MFMA16(ah, wh[kb4], a0);
                a1 = MFMA16(ah, wl[kb4], a1);
                a2 = MFMA16(al, wh[kb4], a2);
            }
            float* pre = kh ? &preB[0][0] : &preA[0][0];
            #pragma unroll
            for (int q = 0; q < 4; ++q)
                pre[(kg * 4 + q) * 64 + n_local] = a0[q] + (a1[q] + a2[q]) * (1.0f / 2048.0f);
            __syncthreads();

            if (tid < 256) {
                f32x4 gA = *(const f32x4*)&preA[cr][cjl * 4];
                f32x4 gB = *(const f32x4*)&preB[cr][cjl * 4];
                float pf = gA[0] + gB[0] + bb[0] + w1f_, pi = gA[1] + gB[1] + bb[1] + w1i_;
                float po = gA[2] + gB[2] + bb[2] + w1o_, pc = gA[3] + gB[3] + bb[3] + w1c_;
                float fg = 1.f / (1.f + expf(-pf));
                float ig = 1.f / (1.f + expf(-pi));
                float og = 1.f / (1.f + expf(-po));
                float ct = tanhf(pc);
                creg = fmaf(fg, creg, ig * ct);
                float h = og * tanhf(creg);
                ASTORE(&y[(size_t)t * BV + (size_t)cb * V + 256 + cjg], h);
                if (t == T - 1) { H1t[cb * NH + cjg] = h; C1t[cb * NH + cjg] = creg; }
            }
        }
    }
}

// Y = H2_all @ Wout + bout, in place (block stages its 64 rows before writing).
__global__ __launch_bounds__(256) void k_ygemm2(
    float* __restrict__ y, const _Float16* __restrict__ pkY,
    const float* __restrict__ bout)
{
    __shared__ _Float16 Ah[64][264];
    __shared__ _Float16 Al[64][264];
    const size_t m0 = (size_t)blockIdx.x * 64;
    const int tid = threadIdx.x;
    for (int idx = tid; idx < 64 * 256; idx += 256) {
        int r = idx >> 8, k = idx & 255;
        float v = y[(m0 + r) * 1024 + k];
        _Float16 hi = (_Float16)v;
        Ah[r][k] = hi;
        Al[r][k] = (_Float16)((v - (float)hi) * 2048.0f);
    }
    __syncthreads();
    const int wave = tid >> 6, lane = tid & 63;
    const int col = lane & 15, kg = lane >> 4;
    const int ar = wave * 16 + col;
    const size_t orow = m0 + wave * 16 + kg * 4;
    for (int npass = 0; npass < 8; ++npass) {
        f32x4 aA[8], aB[8];
        #pragma unroll
        for (int nt = 0; nt < 8; ++nt) { aA[nt] = (f32x4){0.f,0.f,0.f,0.f}; aB[nt] = aA[nt]; }
        for (int kb = 0; kb < 8; ++kb) {
            h8 ah = *(const h8*)&Ah[ar][kb * 32 + kg * 8];
            h8 al = *(const h8*)&Al[ar][kb * 32 + kg * 8];
            #pragma unroll
            for (int nt = 0; nt < 8; ++nt) {
                const int ngrp = npass * 8 + nt;
                const _Float16* pb = pkY + ((size_t)(ngrp * 8 + kb) * 64 + lane) * 8;
                h8 bh = *(const h8*)pb;
                h8 bl = *(const h8*)(pb + 262144);
                aA[nt] = MFMA16(ah, bh, aA[nt]);
                aB[nt] = MFMA16(ah, bl, aB[nt]);
                aB[nt] = MFMA16(al, bh, aB[nt]);
            }
        }
        #pragma unroll
        for (int nt = 0; nt < 8; ++nt) {
            int n = npass * 128 + nt * 16 + col;
            float bbo = bout[n];
            #pragma unroll
            for (int q = 0; q < 4; ++q)
                y[(orow + q) * 1024 + n] = aA[nt][q] + aB[nt][q] * (1.0f / 2048.0f) + bbo;
        }
    }
}

// ---------------- launch ----------------
extern "C" void kernel_launch(void* const* d_in, const int* in_sizes, int n_in,
                              void* d_out, int out_size, void* d_ws, size_t ws_size,
                              hipStream_t stream) {
    const int*   X    = (const int*)  d_in[0];
    const float* H1in = (const float*)d_in[1];
    const float* C1in = (const float*)d_in[2];
    const float* H2in = (const float*)d_in[3];
    const float* C2in = (const float*)d_in[4];
    const float* W1f = (const float*)d_in[5];  const float* b1f = (const float*)d_in[6];
    const float* W1i = (const float*)d_in[7];  const float* b1i = (const float*)d_in[8];
    const float* W1o = (const float*)d_in[9];  const float* b1o = (const float*)d_in[10];
    const float* W1c = (const float*)d_in[11]; const float* b1c = (const float*)d_in[12];
    const float* W2f = (const float*)d_in[13]; const float* b2f = (const float*)d_in[14];
    const float* W2i = (const float*)d_in[15]; const float* b2i = (const float*)d_in[16];
    const float* W2o = (const float*)d_in[17]; const float* b2o = (const float*)d_in[18];
    const float* W2c = (const float*)d_in[19]; const float* b2c = (const float*)d_in[20];
    const float* Wout = (const float*)d_in[21]; const float* bout = (const float*)d_in[22];

    float* y   = (float*)d_out;
    float* H1t = y + YSZ;
    float* C1t = y + YSZ + 1 * 32768;
    float* H2t = y + YSZ + 2 * 32768;
    float* C2t = y + YSZ + 3 * 32768;

    char* ws = (char*)d_ws;
    _Float16* pk2 = (_Float16*)ws;
    _Float16* pk1 = pk2 + 1048576;
    _Float16* pkY = pk1 + 524288;
    float* bp2 = (float*)(ws + 4194304);
    float* bp1 = bp2 + 1024;

    k_prep<<<8200, 256, 0, stream>>>(W1f, W1i, W1o, W1c, W2f, W2i, W2o, W2c, Wout,
                                     b1f, b1i, b1o, b1c, b2f, b2i, b2o, b2c,
                                     pk2, pk1, pkY, bp2, bp1);
    k_sent<<<2048, 256, 0, stream>>>(y);

    k_persist<<<256, 512, 0, stream>>>(X, H1in, C1in, H2in, C2in, y,
                                       H1t, C1t, H2t, C2t,
                                       pk2, pk1, bp2, bp1,
                                       W1f, W1i, W1o, W1c);

    k_ygemm2<<<1024, 256, 0, stream>>>(y, pkY, bout);
}

// Round 8
// 2166.601 us; speedup vs baseline: 3.4758x; 1.2643x over previous
//
#include <hip/hip_runtime.h>
#include <math.h>

static constexpr int V  = 1024;
static constexpr int NH = 256;
static constexpr int B  = 128;
static constexpr int T  = 512;
static constexpr size_t BV  = (size_t)B * V;
static constexpr size_t YSZ = (size_t)T * B * V;   // 67,108,864
static constexpr unsigned SENT = 0xFFC0DEADu;      // NaN payload; h in (-1,1) never equals it

typedef _Float16 h8 __attribute__((ext_vector_type(8)));
typedef _Float16 h4 __attribute__((ext_vector_type(4)));
typedef float f32x4 __attribute__((ext_vector_type(4)));

#define MFMA16(a, b, c) __builtin_amdgcn_mfma_f32_16x16x32_f16((a), (b), (c), 0, 0, 0)
#define ALOAD(p)  __hip_atomic_load((p),  __ATOMIC_RELAXED, __HIP_MEMORY_SCOPE_AGENT)
#define ASTORE(p, v) __hip_atomic_store((p), (v), __ATOMIC_RELAXED, __HIP_MEMORY_SCOPE_AGENT)

__device__ __forceinline__ float fast_sigmoid(float x) {
    // 1/(1+e^-x); arg clamp keeps v_exp in range
    float a = fminf(-1.442695041f * x, 126.0f);
    float e = __builtin_amdgcn_exp2f(a);
    return __builtin_amdgcn_rcpf(1.0f + e);
}

// Split-f16: x = hi + lo*2^-11, lo pre-scaled by 2048. Dot = hi*hi + (hi*lo + lo*hi)*2^-11.
// d_out layout (f32): y[T*B][V], tails: H1, C1, H2, C2 (each B*NH).
// Stash: h2(t)->y[t][0:256], h1(t)->y[t][256:512]; sync = data-as-flag (SENT),
// relaxed agent atomics both sides (bypass L1/L2 -> LLC is the sync point).
// k_persist: 256 blocks x 512 threads (8 waves = 4 n-quarters x 2 K-halves).
// Staging = BATCHED: all poll loads issue up front; retries re-load only failed
// elements as a batch (1 LLC hop instead of 4 serialized per step).

__global__ __launch_bounds__(256) void k_prep(
    const float* __restrict__ W1f, const float* __restrict__ W1i,
    const float* __restrict__ W1o, const float* __restrict__ W1c,
    const float* __restrict__ W2f, const float* __restrict__ W2i,
    const float* __restrict__ W2o, const float* __restrict__ W2c,
    const float* __restrict__ Wout,
    const float* __restrict__ b1f, const float* __restrict__ b1i,
    const float* __restrict__ b1o, const float* __restrict__ b1c,
    const float* __restrict__ b2f, const float* __restrict__ b2i,
    const float* __restrict__ b2o, const float* __restrict__ b2c,
    _Float16* __restrict__ pk2, _Float16* __restrict__ pk1,
    _Float16* __restrict__ pkY, float* __restrict__ bp2, float* __restrict__ bp1)
{
    int idx = blockIdx.x * 256 + threadIdx.x;
    if (idx < 2097152) {
        int KB, e, rowoff = 0;
        bool vocabN = false;
        _Float16* dst;
        if (idx < 1048576)      { e = idx;            KB = 16; dst = pk2; }
        else if (idx < 1572864) { e = idx - 1048576;  KB = 8;  dst = pk1; rowoff = V; }
        else                    { e = idx - 1572864;  KB = 8;  dst = pkY; vocabN = true; }
        int S = 64 * KB * 512;
        int split = e / S, r = e % S;
        int grp = r / (KB * 512);
        int r2  = r % (KB * 512);
        int kb = r2 >> 9, lane = (r2 >> 3) & 63, i = r2 & 7;
        int n = grp * 16 + (lane & 15);
        int k = kb * 32 + (lane >> 4) * 8 + i;
        float val;
        if (vocabN) {
            val = Wout[(size_t)k * 1024 + n];
        } else {
            int j = n >> 2, g = n & 3;
            const float* W = (KB == 16)
                ? (g == 0 ? W2f : g == 1 ? W2i : g == 2 ? W2o : W2c)
                : (g == 0 ? W1f : g == 1 ? W1i : g == 2 ? W1o : W1c);
            val = W[(size_t)(rowoff + k) * NH + j];
        }
        _Float16 hi = (_Float16)val;
        dst[e] = split ? (_Float16)((val - (float)hi) * 2048.0f) : hi;
    } else {
        int bi = idx - 2097152;
        if (bi < 1024) {
            int j = bi >> 2, g = bi & 3;
            bp2[bi] = (g == 0 ? b2f : g == 1 ? b2i : g == 2 ? b2o : b2c)[j];
        } else if (bi < 2048) {
            int b2_ = bi - 1024;
            int j = b2_ >> 2, g = b2_ & 3;
            bp1[b2_] = (g == 0 ? b1f : g == 1 ? b1i : g == 2 ? b1o : b1c)[j];
        }
    }
}

// Fill h-stash (cols 0..511 of every y row) with sentinel.
__global__ __launch_bounds__(256) void k_sent(float* __restrict__ y) {
    const float s = __uint_as_float(SENT);
    const f32x4 sv = {s, s, s, s};
    int gid = blockIdx.x * 256 + threadIdx.x;       // 524288 threads
    for (int n = gid; n < 8388608; n += 524288) {
        int row = n >> 7, c4 = n & 127;
        *(f32x4*)&y[(size_t)row * V + c4 * 4] = sv;
    }
}

__device__ __forceinline__ void cvt4(const float* u, h4* hi4, h4* lo4) {
    h4 hi, lo;
    #pragma unroll
    for (int e = 0; e < 4; ++e) {
        _Float16 h = (_Float16)u[e];
        hi[e] = h; lo[e] = (_Float16)((u[e] - (float)h) * 2048.0f);
    }
    *hi4 = hi; *lo4 = lo;
}

// Persistent recurrence. 256 blocks x 512 thr: bid<128 -> cell2, else cell1.
// Block (mp,np): rows r0..r0+15, gate-cols np*64..+64, all t.
// Wave w: wq=w&3 (16-col group np*4+wq), kh=w>>2 (K-half).
__global__ __launch_bounds__(512, 1) void k_persist(
    const int* __restrict__ X,
    const float* __restrict__ H1in, const float* __restrict__ C1in,
    const float* __restrict__ H2in, const float* __restrict__ C2in,
    float* __restrict__ y,
    float* __restrict__ H1t, float* __restrict__ C1t,
    float* __restrict__ H2t, float* __restrict__ C2t,
    const _Float16* __restrict__ pk2, const _Float16* __restrict__ pk1,
    const float* __restrict__ bp2, const float* __restrict__ bp1,
    const float* __restrict__ W1f, const float* __restrict__ W1i,
    const float* __restrict__ W1o, const float* __restrict__ W1c)
{
    const int bid = blockIdx.x, tid = threadIdx.x;
    const bool isC2 = bid < 128;
    const int mp = (bid & 127) >> 4;    // 0..7
    const int np = bid & 15;            // 0..15
    const int r0 = mp * 16;

    __shared__ _Float16 Ah[16][520];
    __shared__ _Float16 Al[16][520];
    __shared__ float    preA[16][64];
    __shared__ float    preB[16][64];

    const int wave = tid >> 6, lane = tid & 63;
    const int wq = wave & 3, kh = wave >> 2;
    const int col = lane & 15, kg = lane >> 4;
    const _Float16* arow_h = &Ah[col][kg * 8];
    const _Float16* arow_l = &Al[col][kg * 8];
    const int n_local = wq * 16 + col;

    // combine ownership (threads 0..255 only)
    const int cr = tid >> 4, cjl = tid & 15;
    const int cb = r0 + (cr & 15), cjg = np * 16 + cjl;

    if (isC2) {
        // ---- per-wave weights: kb = kh*8 + kb8, 16 h8 = 64 VGPR ----
        h8 wh[8], wl[8];
        {
            const _Float16* pB = pk2 + ((size_t)((np * 4 + wq) * 16 + kh * 8) * 64 + lane) * 8;
            #pragma unroll
            for (int kb8 = 0; kb8 < 8; ++kb8) {
                wh[kb8] = *(const h8*)(pB + (size_t)kb8 * 512);
                wl[kb8] = *(const h8*)(pB + 524288 + (size_t)kb8 * 512);
            }
            #pragma unroll
            for (int kb8 = 0; kb8 < 8; ++kb8)
                asm volatile("" : "+v"(wh[kb8]), "+v"(wl[kb8]));
        }
        float creg = (tid < 256) ? C2in[cb * NH + cjg] : 0.f;
        const f32x4 bb = *(const f32x4*)&bp2[np * 64 + cjl * 4];

        // staging: sk4 = tid&127 (cols: <64 -> h1(t), >=64 -> h2(t-1)); rows g*4+srb
        const int sk4 = tid & 127;
        const int srb = tid >> 7;   // 0..3
        const bool isH1 = sk4 < 64;

        for (int t = 0; t < T; ++t) {
            // ---- batched poll+stage ----
            const float* sp[4];
            float u[4][4];
            const bool pollable = isH1 || (t > 0);
            #pragma unroll
            for (int g = 0; g < 4; ++g) {
                const int r = g * 4 + srb;
                sp[g] = isH1 ? (y + (size_t)t * BV + (size_t)(r0 + r) * V + 256 + sk4 * 4)
                       : (t ? (y + (size_t)(t - 1) * BV + (size_t)(r0 + r) * V + (sk4 - 64) * 4)
                            : (H2in + (size_t)(r0 + r) * NH + (sk4 - 64) * 4));
            }
            #pragma unroll
            for (int g = 0; g < 4; ++g)
                #pragma unroll
                for (int e = 0; e < 4; ++e) u[g][e] = ALOAD(sp[g] + e);
            if (pollable) {
                for (;;) {
                    bool any = false;
                    #pragma unroll
                    for (int g = 0; g < 4; ++g)
                        #pragma unroll
                        for (int e = 0; e < 4; ++e)
                            any = any || (__float_as_uint(u[g][e]) == SENT);
                    if (!any) break;
                    __builtin_amdgcn_s_sleep(1);
                    #pragma unroll
                    for (int g = 0; g < 4; ++g)
                        #pragma unroll
                        for (int e = 0; e < 4; ++e)
                            if (__float_as_uint(u[g][e]) == SENT) u[g][e] = ALOAD(sp[g] + e);
                }
            }
            #pragma unroll
            for (int g = 0; g < 4; ++g) {
                const int r = g * 4 + srb;
                cvt4(u[g], (h4*)&Ah[r][sk4 * 4], (h4*)&Al[r][sk4 * 4]);
            }
            __syncthreads();

            f32x4 a0 = {0.f, 0.f, 0.f, 0.f}, a1 = a0, a2 = a0;
            #pragma unroll
            for (int kb8 = 0; kb8 < 8; ++kb8) {
                const int kbg = kh * 8 + kb8;
                h8 ah = *(const h8*)(arow_h + kbg * 32);
                h8 al = *(const h8*)(arow_l + kbg * 32);
                a0 = MFMA16(ah, wh[kb8], a0);
                a1 = MFMA16(ah, wl[kb8], a1);
                a2 = MFMA16(al, wh[kb8], a2);
            }
            float* pre = kh ? &preB[0][0] : &preA[0][0];
            #pragma unroll
            for (int q = 0; q < 4; ++q)
                pre[(kg * 4 + q) * 64 + n_local] = a0[q] + (a1[q] + a2[q]) * (1.0f / 2048.0f);
            __syncthreads();

            if (tid < 256) {
                f32x4 gA = *(const f32x4*)&preA[cr][cjl * 4];
                f32x4 gB = *(const f32x4*)&preB[cr][cjl * 4];
                float pf = gA[0] + gB[0] + bb[0], pi = gA[1] + gB[1] + bb[1];
                float po = gA[2] + gB[2] + bb[2], pc = gA[3] + gB[3] + bb[3];
                float fg = fast_sigmoid(pf);
                float ig = fast_sigmoid(pi);
                float og = fast_sigmoid(po);
                float ct = tanhf(pc);
                creg = fmaf(fg, creg, ig * ct);
                float h = og * tanhf(creg);
                ASTORE(&y[(size_t)t * BV + (size_t)cb * V + cjg], h);
                if (t == T - 1) { H2t[cb * NH + cjg] = h; C2t[cb * NH + cjg] = creg; }
            }
        }
    } else {
        // ---- per-wave weights: kb = kh*4 + kb4, 8 h8 = 32 VGPR ----
        h8 wh[4], wl[4];
        {
            const _Float16* pB = pk1 + ((size_t)((np * 4 + wq) * 8 + kh * 4) * 64 + lane) * 8;
            #pragma unroll
            for (int kb4 = 0; kb4 < 4; ++kb4) {
                wh[kb4] = *(const h8*)(pB + (size_t)kb4 * 512);
                wl[kb4] = *(const h8*)(pB + 262144 + (size_t)kb4 * 512);
            }
            #pragma unroll
            for (int kb4 = 0; kb4 < 4; ++kb4)
                asm volatile("" : "+v"(wh[kb4]), "+v"(wl[kb4]));
        }
        float creg = (tid < 256) ? C1in[cb * NH + cjg] : 0.f;
        const f32x4 bb = *(const f32x4*)&bp1[np * 64 + cjl * 4];

        // staging: sk4 = tid&63, rows srb + g*8
        const int sk4 = tid & 63;
        const int srb = tid >> 6;   // 0..7

        for (int t = 0; t < T; ++t) {
            // early-issue token-row gathers (consumed in combine)
            float w1f_ = 0.f, w1i_ = 0.f, w1o_ = 0.f, w1c_ = 0.f;
            if (tid < 256) {
                int tok = X[cb * T + t];
                w1f_ = W1f[(size_t)tok * NH + cjg];
                w1i_ = W1i[(size_t)tok * NH + cjg];
                w1o_ = W1o[(size_t)tok * NH + cjg];
                w1c_ = W1c[(size_t)tok * NH + cjg];
            }
            // ---- batched poll+stage h1(t-1) ----
            const float* sp[2];
            float u[2][4];
            #pragma unroll
            for (int g = 0; g < 2; ++g) {
                const int r = g * 8 + srb;
                sp[g] = t ? (y + (size_t)(t - 1) * BV + (size_t)(r0 + r) * V + 256 + sk4 * 4)
                          : (H1in + (size_t)(r0 + r) * NH + sk4 * 4);
            }
            #pragma unroll
            for (int g = 0; g < 2; ++g)
                #pragma unroll
                for (int e = 0; e < 4; ++e) u[g][e] = ALOAD(sp[g] + e);
            if (t) {
                for (;;) {
                    bool any = false;
                    #pragma unroll
                    for (int g = 0; g < 2; ++g)
                        #pragma unroll
                        for (int e = 0; e < 4; ++e)
                            any = any || (__float_as_uint(u[g][e]) == SENT);
                    if (!any) break;
                    __builtin_amdgcn_s_sleep(1);
                    #pragma unroll
                    for (int g = 0; g < 2; ++g)
                        #pragma unroll
                        for (int e = 0; e < 4; ++e)
                            if (__float_as_uint(u[g][e]) == SENT) u[g][e] = ALOAD(sp[g] + e);
                }
            }
            #pragma unroll
            for (int g = 0; g < 2; ++g) {
                const int r = g * 8 + srb;
                cvt4(u[g], (h4*)&Ah[r][sk4 * 4], (h4*)&Al[r][sk4 * 4]);
            }
            __syncthreads();

            f32x4 a0 = {0.f, 0.f, 0.f, 0.f}, a1 = a0, a2 = a0;
            #pragma unroll
            for (int kb4 = 0; kb4 < 4; ++kb4) {
                const int kbg = kh * 4 + kb4;
                h8 ah = *(const h8*)(arow_h + kbg * 32);
                h8 al = *(const h8*)(arow_l + kbg * 32);
                a0 = MFMA16(ah, wh[kb4], a0);
                a1 = MFMA16(ah, wl[kb4], a1);
                a2 = MFMA16(al, wh[kb4], a2);
            }
            float* pre = kh ? &preB[0][0] : &preA[0][0];
            #pragma unroll
            for (int q = 0; q < 4; ++q)
                pre[(kg * 4 + q) * 64 + n_local] = a0[q] + (a1[q] + a2[q]) * (1.0f / 2048.0f);
            __syncthreads();

            if (tid < 256) {
                f32x4 gA = *(const f32x4*)&preA[cr][cjl * 4];
                f32x4 gB = *(const f32x4*)&preB[cr][cjl * 4];
                float pf = gA[0] + gB[0] + bb[0] + w1f_, pi = gA[1] + gB[1] + bb[1] + w1i_;
                float po = gA[2] + gB[2] + bb[2] + w1o_, pc = gA[3] + gB[3] + bb[3] + w1c_;
                float fg = fast_sigmoid(pf);
                float ig = fast_sigmoid(pi);
                float og = fast_sigmoid(po);
                float ct = tanhf(pc);
                creg = fmaf(fg, creg, ig * ct);
                float h = og * tanhf(creg);
                ASTORE(&y[(size_t)t * BV + (size_t)cb * V + 256 + cjg], h);
                if (t == T - 1) { H1t[cb * NH + cjg] = h; C1t[cb * NH + cjg] = creg; }
            }
        }
    }
}

// Y = H2_all @ Wout + bout, in place (block stages its 64 rows before writing).
__global__ __launch_bounds__(256) void k_ygemm2(
    float* __restrict__ y, const _Float16* __restrict__ pkY,
    const float* __restrict__ bout)
{
    __shared__ _Float16 Ah[64][264];
    __shared__ _Float16 Al[64][264];
    const size_t m0 = (size_t)blockIdx.x * 64;
    const int tid = threadIdx.x;
    for (int idx = tid; idx < 64 * 256; idx += 256) {
        int r = idx >> 8, k = idx & 255;
        float v = y[(m0 + r) * 1024 + k];
        _Float16 hi = (_Float16)v;
        Ah[r][k] = hi;
        Al[r][k] = (_Float16)((v - (float)hi) * 2048.0f);
    }
    __syncthreads();
    const int wave = tid >> 6, lane = tid & 63;
    const int col = lane & 15, kg = lane >> 4;
    const int ar = wave * 16 + col;
    const size_t orow = m0 + wave * 16 + kg * 4;
    for (int npass = 0; npass < 8; ++npass) {
        f32x4 aA[8], aB[8];
        #pragma unroll
        for (int nt = 0; nt < 8; ++nt) { aA[nt] = (f32x4){0.f,0.f,0.f,0.f}; aB[nt] = aA[nt]; }
        for (int kb = 0; kb < 8; ++kb) {
            h8 ah = *(const h8*)&Ah[ar][kb * 32 + kg * 8];
            h8 al = *(const h8*)&Al[ar][kb * 32 + kg * 8];
            #pragma unroll
            for (int nt = 0; nt < 8; ++nt) {
                const int ngrp = npass * 8 + nt;
                const _Float16* pb = pkY + ((size_t)(ngrp * 8 + kb) * 64 + lane) * 8;
                h8 bh = *(const h8*)pb;
                h8 bl = *(const h8*)(pb + 262144);
                aA[nt] = MFMA16(ah, bh, aA[nt]);
                aB[nt] = MFMA16(ah, bl, aB[nt]);
                aB[nt] = MFMA16(al, bh, aB[nt]);
            }
        }
        #pragma unroll
        for (int nt = 0; nt < 8; ++nt) {
            int n = npass * 128 + nt * 16 + col;
            float bbo = bout[n];
            #pragma unroll
            for (int q = 0; q < 4; ++q)
                y[(orow + q) * 1024 + n] = aA[nt][q] + aB[nt][q] * (1.0f / 2048.0f) + bbo;
        }
    }
}

// ---------------- launch ----------------
extern "C" void kernel_launch(void* const* d_in, const int* in_sizes, int n_in,
                              void* d_out, int out_size, void* d_ws, size_t ws_size,
                              hipStream_t stream) {
    const int*   X    = (const int*)  d_in[0];
    const float* H1in = (const float*)d_in[1];
    const float* C1in = (const float*)d_in[2];
    const float* H2in = (const float*)d_in[3];
    const float* C2in = (const float*)d_in[4];
    const float* W1f = (const float*)d_in[5];  const float* b1f = (const float*)d_in[6];
    const float* W1i = (const float*)d_in[7];  const float* b1i = (const float*)d_in[8];
    const float* W1o = (const float*)d_in[9];  const float* b1o = (const float*)d_in[10];
    const float* W1c = (const float*)d_in[11]; const float* b1c = (const float*)d_in[12];
    const float* W2f = (const float*)d_in[13]; const float* b2f = (const float*)d_in[14];
    const float* W2i = (const float*)d_in[15]; const float* b2i = (const float*)d_in[16];
    const float* W2o = (const float*)d_in[17]; const float* b2o = (const float*)d_in[18];
    const float* W2c = (const float*)d_in[19]; const float* b2c = (const float*)d_in[20];
    const float* Wout = (const float*)d_in[21]; const float* bout = (const float*)d_in[22];

    float* y   = (float*)d_out;
    float* H1t = y + YSZ;
    float* C1t = y + YSZ + 1 * 32768;
    float* H2t = y + YSZ + 2 * 32768;
    float* C2t = y + YSZ + 3 * 32768;

    char* ws = (char*)d_ws;
    _Float16* pk2 = (_Float16*)ws;
    _Float16* pk1 = pk2 + 1048576;
    _Float16* pkY = pk1 + 524288;
    float* bp2 = (float*)(ws + 4194304);
    float* bp1 = bp2 + 1024;

    k_prep<<<8200, 256, 0, stream>>>(W1f, W1i, W1o, W1c, W2f, W2i, W2o, W2c, Wout,
                                     b1f, b1i, b1o, b1c, b2f, b2i, b2o, b2c,
                                     pk2, pk1, pkY, bp2, bp1);
    k_sent<<<2048, 256, 0, stream>>>(y);

    k_persist<<<256, 512, 0, stream>>>(X, H1in, C1in, H2in, C2in, y,
                                       H1t, C1t, H2t, C2t,
                                       pk2, pk1, bp2, bp1,
                                       W1f, W1i, W1o, W1c);

    k_ygemm2<<<1024, 256, 0, stream>>>(y, pkY, bout);
}